// Round 3
// baseline (291.210 us; speedup 1.0000x reference)
//
#include <hip/hip_runtime.h>
#include <math.h>

#define D 256
#define NX 16
#define L 2048
#define NBATCH 8
#define NTOK (NBATCH * L)
#define CL 32
#define NCH (L / CL)  // 64
#define LOG2E 1.44269504088896340736f

typedef float f32x4 __attribute__((ext_vector_type(4)));
// Fragment type for mfma_f32_16x16x32_bf16 on gfx950: 8 bf16 as 8 shorts.
typedef short bf16x8 __attribute__((ext_vector_type(8)));

// round-to-nearest-even f32 -> bf16 (as ushort bits)
__device__ __forceinline__ unsigned short f2bf(float x) {
  unsigned u = __float_as_uint(x);
  u = u + 0x7fffu + ((u >> 16) & 1u);
  return (unsigned short)(u >> 16);
}
__device__ __forceinline__ float bf2f(unsigned short h) {
  return __uint_as_float(((unsigned)h) << 16);
}

// ---------------- K0: At/Wbct prep + W1/W2 hi-lo bf16 fragment packing ------
// Fragment K-enumeration shared by A and B operands: element j of lane l
// covers k = s*32 + 8*(l>>4) + j; 16-dim = lane&15. Valid for any HW k-map.
__global__ __launch_bounds__(256) void k0_prep(const float* __restrict__ A,
                                               const float* __restrict__ WB,
                                               const float* __restrict__ WC,
                                               const float* __restrict__ W1,
                                               const float* __restrict__ W2,
                                               float* __restrict__ At,
                                               float* __restrict__ Wbct,
                                               unsigned short* __restrict__ W1fh,
                                               unsigned short* __restrict__ W1fl,
                                               unsigned short* __restrict__ W2fh,
                                               unsigned short* __restrict__ W2fl) {
  int i = blockIdx.x * 256 + threadIdx.x;  // 86016 total
  if (i < 4096) {
    int d = i >> 4, n = i & 15;
    At[n * D + d] = A[i] * LOG2E;
  } else if (i < 12288) {
    int j = i - 4096;  // 8192
    int d = j >> 5, c = j & 31;
    Wbct[j] = (c < 16) ? WB[c * D + d] : WC[(c - 16) * D + d];
  } else if (i < 77824) {
    // W1 frags: e = ((s*16 + t)*64 + l)*8 + j ; 65536 elems
    int e = i - 12288;
    int j = e & 7, l = (e >> 3) & 63, tt = (e >> 9) & 15, s = e >> 13;
    int k = s * 32 + ((l >> 4) << 3) + j;
    int n = tt * 16 + (l & 15);
    float x = W1[k * 256 + n];
    unsigned short h = f2bf(x);
    W1fh[e] = h;
    W1fl[e] = f2bf(x - bf2f(h));
  } else {
    // W2 frags: e = ((s*2 + t)*64 + l)*8 + j ; 8192 elems
    int e = i - 77824;
    int j = e & 7, l = (e >> 3) & 63, tt = (e >> 9) & 1, s = e >> 10;
    int k = s * 32 + ((l >> 4) << 3) + j;
    int n = tt * 16 + (l & 15);
    float x = W2[k * 32 + n];
    unsigned short h = f2bf(x);
    W2fh[e] = h;
    W2fl[e] = f2bf(x - bf2f(h));
  }
}

// ---------------- K1A: front end (h, LN, delta, Bm/Cm), 16 tok/block -------
// grid 1024, 4 blocks/CU (launch_bounds cap 128 VGPR) -> 16 waves/CU.
__global__ __launch_bounds__(256, 4) void k1a_front(
    const float* __restrict__ y, const float* __restrict__ Win,
    const float* __restrict__ bin_, const float* __restrict__ ng,
    const float* __restrict__ nb, const float* __restrict__ Wbct,
    const float* __restrict__ qd, const float* __restrict__ pd,
    float* __restrict__ hn, float* __restrict__ delta,
    float* __restrict__ Bm, float* __restrict__ Cm,
    float* __restrict__ muv, float* __restrict__ irsv) {
  __shared__ float sy[16][32];
  __shared__ float sh[16][260];     // hn tile, pitch 260
  __shared__ float sph[2 * 16 * 32];  // phase-C half-K partials
  int t = threadIdx.x;
  int tok0 = blockIdx.x * 16;
  if (t < 128)
    ((float4*)sy)[t] = ((const float4*)(y + (size_t)tok0 * 32))[t];
  __syncthreads();
  int dcol = t & 63;
  int w = t >> 6;                    // wave -> tokens w*4..w*4+3
  int d4 = dcol * 4;
  float4 bv = ((const float4*)bin_)[dcol];
  float4 acc[4];
  #pragma unroll
  for (int jj = 0; jj < 4; ++jj) acc[jj] = bv;
  const float4* Win4 = (const float4*)Win;
  #pragma unroll
  for (int k = 0; k < 32; ++k) {
    float4 wv = Win4[k * 64 + dcol];
    #pragma unroll
    for (int jj = 0; jj < 4; ++jj) {
      float av = sy[w * 4 + jj][k];
      acc[jj].x = fmaf(av, wv.x, acc[jj].x);
      acc[jj].y = fmaf(av, wv.y, acc[jj].y);
      acc[jj].z = fmaf(av, wv.z, acc[jj].z);
      acc[jj].w = fmaf(av, wv.w, acc[jj].w);
    }
  }
  float4 g4 = ((const float4*)ng)[dcol];
  float4 nb4 = ((const float4*)nb)[dcol];
  float4 q4 = ((const float4*)qd)[dcol];
  float pd0 = pd[0];
  #pragma unroll
  for (int jj = 0; jj < 4; ++jj) {
    int j = w * 4 + jj;
    int tok = tok0 + j;
    float4 a = acc[jj];
    float s1 = a.x + a.y + a.z + a.w;
    float s2 = a.x * a.x + a.y * a.y + a.z * a.z + a.w * a.w;
    #pragma unroll
    for (int off = 1; off < 64; off <<= 1) {
      s1 += __shfl_xor(s1, off);
      s2 += __shfl_xor(s2, off);
    }
    float mu = s1 * (1.f / D);
    float var = s2 * (1.f / D) - mu * mu;
    float rstd = rsqrtf(var + 1e-5f);
    if (dcol == 0) { muv[tok] = mu; irsv[tok] = sqrtf(var + 1e-5f); }
    float4 v4;
    v4.x = (a.x - mu) * rstd * g4.x + nb4.x;
    v4.y = (a.y - mu) * rstd * g4.y + nb4.y;
    v4.z = (a.z - mu) * rstd * g4.z + nb4.z;
    v4.w = (a.w - mu) * rstd * g4.w + nb4.w;
    ((float4*)(hn + (size_t)tok * D))[dcol] = v4;
    *(float4*)&sh[j][d4] = v4;
    float dd = v4.x * q4.x + v4.y * q4.y + v4.z * q4.z + v4.w * q4.w;
    #pragma unroll
    for (int off = 1; off < 64; off <<= 1) dd += __shfl_xor(dd, off);
    if (dcol == 0) {
      float xx = pd0 + dd;
      delta[tok] = (xx > 20.f) ? xx : log1pf(expf(xx));
    }
  }
  __syncthreads();
  // Phase C: [Bm|Cm](16x32) = sh(16x256) @ Wbct(256x32); K split across 2 halves
  int c4 = t & 7;
  int jc = (t >> 3) & 15;
  int hk = t >> 7;  // 0/1
  const float* shrow = &sh[jc][hk * 128];
  const float4* W4 = (const float4*)Wbct + (size_t)hk * 128 * 8;
  float4 o = make_float4(0.f, 0.f, 0.f, 0.f);
  #pragma unroll 8
  for (int k = 0; k < 128; ++k) {
    float av = shrow[k];
    float4 wv = W4[k * 8 + c4];
    o.x = fmaf(av, wv.x, o.x);
    o.y = fmaf(av, wv.y, o.y);
    o.z = fmaf(av, wv.z, o.z);
    o.w = fmaf(av, wv.w, o.w);
  }
  *(float4*)&sph[(((hk << 4) | jc) << 5) + c4 * 4] = o;
  __syncthreads();
  if (t < 128) {
    int j2 = t >> 3, cc = t & 7;
    float4 r0 = *(float4*)&sph[(j2 << 5) + cc * 4];
    float4 r1 = *(float4*)&sph[((16 + j2) << 5) + cc * 4];
    float4 r;
    r.x = r0.x + r1.x; r.y = r0.y + r1.y;
    r.z = r0.z + r1.z; r.w = r0.w + r1.w;
    int tokj = tok0 + j2;
    if (cc < 4) ((float4*)(Bm + (size_t)tokj * NX))[cc] = r;
    else        ((float4*)(Cm + (size_t)tokj * NX))[cc - 4] = r;
  }
}

// ---------------- K1S: zero-state local chunk scan -> EX end states, T -----
__global__ __launch_bounds__(256) void k1s_scan(
    const float* __restrict__ hn, const float* __restrict__ delta,
    const float* __restrict__ Bm, const float* __restrict__ At,
    float* __restrict__ EX, float* __restrict__ T) {
  __shared__ float sh[32][260];
  __shared__ float sB[32][NX];
  __shared__ float sdelta[32];
  int t = threadIdx.x;
  int tok0 = blockIdx.x * 32;
  const float4* hn4 = (const float4*)(hn + (size_t)tok0 * D);
  for (int i = t; i < 2048; i += 256) {
    int row = i >> 6, c4 = i & 63;
    *(float4*)&sh[row][c4 * 4] = hn4[i];
  }
  for (int i = t; i < 32 * NX; i += 256)
    ((float*)sB)[i] = Bm[(size_t)tok0 * NX + i];
  if (t < 32) sdelta[t] = delta[tok0 + t];
  __syncthreads();
  if (t < 32) {
    float v = sdelta[t];
    #pragma unroll
    for (int off = 1; off < 32; off <<= 1) v += __shfl_xor(v, off);
    if (t == 0) T[blockIdx.x] = v;
  }
  float a16[16];
  #pragma unroll
  for (int n = 0; n < 16; ++n) a16[n] = At[n * D + t];
  float x16[16];
  #pragma unroll
  for (int n = 0; n < 16; ++n) x16[n] = 0.f;
  for (int lo = 0; lo < CL; ++lo) {
    float dlt = sdelta[lo];
    float du = dlt * sh[lo][t];
    #pragma unroll
    for (int n = 0; n < 16; ++n)
      x16[n] = fmaf(exp2f(dlt * a16[n]), x16[n], du * sB[lo][n]);
  }
  size_t exbase = (size_t)blockIdx.x * (NX * D) + t;
  #pragma unroll
  for (int n = 0; n < 16; ++n) EX[exbase + n * D] = x16[n];
}

// ---------------- K2b: chunk-level scan, 64-thr blocks (all CUs busy) ------
__global__ __launch_bounds__(64) void k2b_chunkscan(
    const float* __restrict__ At, const float* __restrict__ T,
    float* __restrict__ EX) {
  __shared__ float sT[NCH];
  int b = blockIdx.x >> 6;
  int rem = ((blockIdx.x & 63) << 6) | threadIdx.x;  // n*D + d
  sT[threadIdx.x] = T[b * NCH + threadIdx.x];
  __syncthreads();
  float A2 = At[rem];  // already *LOG2E
  size_t base = ((size_t)b << 18) + rem;
  float eq[4];
  #pragma unroll
  for (int j = 0; j < 4; ++j) eq[j] = EX[base + ((size_t)j << 12)];
  float x = 0.f;
  #pragma unroll 4
  for (int c = 0; c < NCH; ++c) {
    float e = eq[c & 3];
    if (c + 4 < NCH) eq[c & 3] = EX[base + ((size_t)(c + 4) << 12)];
    EX[base + ((size_t)c << 12)] = x;
    x = fmaf(exp2f(sT[c] * A2), x, e);
  }
}

__device__ __forceinline__ float gelu_exact(float x) {
  return 0.5f * x * (1.f + erff(x * 0.70710678118654752440f));
}

// ---------------- K2cd: fixup scan + h recon + LN2 + MFMA MLP ---------------
// bf16 hi/lo split MFMA, now FULL 4-term (Ah*Bh + Al*Bh + Ah*Bl + Al*Bl):
// residual ~2^-18 rel (f32-level). XOR-swizzled LDS A-tiles; W1/W2 fragments
// pre-packed (k0) with the same K-enumeration as the A-frag reads.
__global__ __launch_bounds__(256) void k2cd_scan_mlp(
    const float* __restrict__ hn, const float* __restrict__ delta,
    const float* __restrict__ Bm, const float* __restrict__ Cm,
    const float* __restrict__ At, const float* __restrict__ EX,
    const float* __restrict__ muv, const float* __restrict__ irsv,
    const float* __restrict__ ng, const float* __restrict__ nb,
    const float* __restrict__ nfg, const float* __restrict__ nfb,
    const unsigned short* __restrict__ W1fh, const unsigned short* __restrict__ W1fl,
    const unsigned short* __restrict__ W2fh, const unsigned short* __restrict__ W2fl,
    const float* __restrict__ b1, const float* __restrict__ b2,
    float* __restrict__ out) {
  __shared__ float s_az[32 * 260];                       // scan output (pre-LN2)
  __shared__ __align__(16) unsigned short sAh[32 * 256]; // bf16 hi (a-tile, then z)
  __shared__ __align__(16) unsigned short sAl[32 * 256]; // bf16 lo
  __shared__ float sB[32][NX];
  __shared__ float sC[32][NX];
  __shared__ float sdelta[32];
  __shared__ float smu[32];
  __shared__ float sirs[32];
  int t = threadIdx.x;
  int tok0 = blockIdx.x * 32;  // blockIdx.x == global chunk index
  size_t tokbase = (size_t)tok0;
  if (t < 32) {
    sdelta[t] = delta[tokbase + t];
    smu[t] = muv[tokbase + t];
    sirs[t] = irsv[tokbase + t];
  }
  for (int i = t; i < 32 * NX; i += 256) {
    ((float*)sB)[i] = Bm[tokbase * NX + i];
    ((float*)sC)[i] = Cm[tokbase * NX + i];
  }
  float a16[16], x16[16];
  size_t exbase = (size_t)blockIdx.x * (NX * D) + t;
  #pragma unroll
  for (int n = 0; n < 16; ++n) {
    a16[n] = At[n * D + t];
    x16[n] = EX[exbase + n * D];
  }
  float nb_d = nb[t];
  float invg = 1.0f / ng[t];
  __syncthreads();
  // scan with true entering state; hn read straight from global (used once)
  for (int lo = 0; lo < CL; ++lo) {
    float hv = hn[(tokbase + lo) * D + t];  // coalesced 1 KB/wave
    float dlt = sdelta[lo];
    float du = dlt * hv;
    float p = 0.f;
    #pragma unroll
    for (int n = 0; n < 16; ++n) {
      x16[n] = fmaf(exp2f(dlt * a16[n]), x16[n], du * sB[lo][n]);
      p = fmaf(x16[n], sC[lo][n], p);
    }
    float h = fmaf((hv - nb_d) * invg, sirs[lo], smu[lo]);
    s_az[lo * 260 + t] = h + p;  // final pre-LN2 value
  }
  __syncthreads();
  // LN2 (wave w owns tokens w*8..+7) -> bf16 hi/lo A-tile, XOR-swizzled
  int dcol = t & 63, jrow = t >> 6;
  int d4 = dcol * 4, j8 = jrow * 8;
  {
    float4 g4 = ((const float4*)nfg)[dcol];
    float4 b4 = ((const float4*)nfb)[dcol];
    for (int jj = 0; jj < 8; ++jj) {
      int lo = j8 + jj;
      float4 v = *(float4*)&s_az[lo * 260 + d4];
      float s1 = v.x + v.y + v.z + v.w;
      float s2 = v.x * v.x + v.y * v.y + v.z * v.z + v.w * v.w;
      #pragma unroll
      for (int off = 1; off < 64; off <<= 1) {
        s1 += __shfl_xor(s1, off);
        s2 += __shfl_xor(s2, off);
      }
      float mu2 = s1 * (1.f / D);
      float var2 = s2 * (1.f / D) - mu2 * mu2;
      float rstd2 = rsqrtf(var2 + 1e-5f);
      float4 o;
      o.x = (v.x - mu2) * rstd2 * g4.x + b4.x;
      o.y = (v.y - mu2) * rstd2 * g4.y + b4.y;
      o.z = (v.z - mu2) * rstd2 * g4.z + b4.z;
      o.w = (v.w - mu2) * rstd2 * g4.w + b4.w;
      unsigned short h0 = f2bf(o.x), h1 = f2bf(o.y), h2 = f2bf(o.z), h3 = f2bf(o.w);
      unsigned short q0 = f2bf(o.x - bf2f(h0));
      unsigned short q1 = f2bf(o.y - bf2f(h1));
      unsigned short q2 = f2bf(o.z - bf2f(h2));
      unsigned short q3 = f2bf(o.w - bf2f(h3));
      unsigned off16 = ((unsigned)(d4 * 2)) ^ ((unsigned)(lo & 7) << 4);
      uint2 hv2, lv2;
      hv2.x = (unsigned)h0 | ((unsigned)h1 << 16);
      hv2.y = (unsigned)h2 | ((unsigned)h3 << 16);
      lv2.x = (unsigned)q0 | ((unsigned)q1 << 16);
      lv2.y = (unsigned)q2 | ((unsigned)q3 << 16);
      *(uint2*)((char*)sAh + lo * 512 + off16) = hv2;
      *(uint2*)((char*)sAl + lo * 512 + off16) = lv2;
    }
  }
  __syncthreads();
  // ---- GEMM1: (32x256) @ W1 (256x256), wave w owns cols [w*64, w*64+64) ----
  int l = t & 63, w = t >> 6;
  const bf16x8* B1h = (const bf16x8*)W1fh;
  const bf16x8* B1l = (const bf16x8*)W1fl;
  f32x4 acc[2][4];
  #pragma unroll
  for (int m = 0; m < 2; ++m)
    #pragma unroll
    for (int n = 0; n < 4; ++n) {
      f32x4 z4 = {0.f, 0.f, 0.f, 0.f};
      acc[m][n] = z4;
    }
  #pragma unroll 2
  for (int s = 0; s < 8; ++s) {
    bf16x8 ah[2], al[2];
    #pragma unroll
    for (int m = 0; m < 2; ++m) {
      int row = m * 16 + (l & 15);
      unsigned off16 = ((unsigned)(s * 64 + ((l >> 4) << 4))) ^ ((unsigned)(row & 7) << 4);
      ah[m] = *(const bf16x8*)((const char*)sAh + row * 512 + off16);
      al[m] = *(const bf16x8*)((const char*)sAl + row * 512 + off16);
    }
    #pragma unroll
    for (int n = 0; n < 4; ++n) {
      int bi = (s * 16 + w * 4 + n) * 64 + l;
      bf16x8 bh = B1h[bi];
      bf16x8 bl = B1l[bi];
      #pragma unroll
      for (int m = 0; m < 2; ++m) {
        acc[m][n] = __builtin_amdgcn_mfma_f32_16x16x32_bf16(ah[m], bh, acc[m][n], 0, 0, 0);
        acc[m][n] = __builtin_amdgcn_mfma_f32_16x16x32_bf16(al[m], bh, acc[m][n], 0, 0, 0);
        acc[m][n] = __builtin_amdgcn_mfma_f32_16x16x32_bf16(ah[m], bl, acc[m][n], 0, 0, 0);
        acc[m][n] = __builtin_amdgcn_mfma_f32_16x16x32_bf16(al[m], bl, acc[m][n], 0, 0, 0);
      }
    }
  }
  __syncthreads();  // all A-tile reads done; sAh/sAl now reused for z
  // ---- b1 + gelu + convert -> z (bf16 hi/lo) back into sAh/sAl ----
  #pragma unroll
  for (int n = 0; n < 4; ++n) {
    int colz = w * 64 + n * 16 + (l & 15);
    float b1v = b1[colz];
    #pragma unroll
    for (int m = 0; m < 2; ++m) {
      #pragma unroll
      for (int r = 0; r < 4; ++r) {
        int row = m * 16 + ((l >> 4) << 2) + r;  // C/D: row=(lane>>4)*4+reg
        float zv = gelu_exact(acc[m][n][r] + b1v);
        unsigned short zh = f2bf(zv);
        unsigned short zl = f2bf(zv - bf2f(zh));
        unsigned off16 = ((unsigned)(colz * 2)) ^ ((unsigned)(row & 7) << 4);
        *(unsigned short*)((char*)sAh + row * 512 + off16) = zh;
        *(unsigned short*)((char*)sAl + row * 512 + off16) = zl;
      }
    }
  }
  __syncthreads();
  // ---- GEMM2: z (32x256) @ W2 (256x32); wave w -> (mw=w>>1, nw=w&1) ----
  int mw = w >> 1, nw = w & 1;
  const bf16x8* B2h = (const bf16x8*)W2fh;
  const bf16x8* B2l = (const bf16x8*)W2fl;
  f32x4 acc2 = {0.f, 0.f, 0.f, 0.f};
  #pragma unroll 2
  for (int s = 0; s < 8; ++s) {
    int row = mw * 16 + (l & 15);
    unsigned off16 = ((unsigned)(s * 64 + ((l >> 4) << 4))) ^ ((unsigned)(row & 7) << 4);
    bf16x8 zh8 = *(const bf16x8*)((const char*)sAh + row * 512 + off16);
    bf16x8 zl8 = *(const bf16x8*)((const char*)sAl + row * 512 + off16);
    int bi = (s * 2 + nw) * 64 + l;
    bf16x8 bh = B2h[bi];
    bf16x8 bl = B2l[bi];
    acc2 = __builtin_amdgcn_mfma_f32_16x16x32_bf16(zh8, bh, acc2, 0, 0, 0);
    acc2 = __builtin_amdgcn_mfma_f32_16x16x32_bf16(zl8, bh, acc2, 0, 0, 0);
    acc2 = __builtin_amdgcn_mfma_f32_16x16x32_bf16(zh8, bl, acc2, 0, 0, 0);
    acc2 = __builtin_amdgcn_mfma_f32_16x16x32_bf16(zl8, bl, acc2, 0, 0, 0);
  }
  int colo = nw * 16 + (l & 15);
  float b2v = b2[colo];
  #pragma unroll
  for (int r = 0; r < 4; ++r) {
    int row = mw * 16 + ((l >> 4) << 2) + r;
    out[(size_t)(tok0 + row) * 32 + colo] = acc2[r] + b2v;
  }
}

extern "C" void kernel_launch(void* const* d_in, const int* in_sizes, int n_in,
                              void* d_out, int out_size, void* d_ws, size_t ws_size,
                              hipStream_t stream) {
  const float* y    = (const float*)d_in[0];
  const float* Win  = (const float*)d_in[1];
  const float* bin_ = (const float*)d_in[2];
  const float* ng   = (const float*)d_in[3];
  const float* nb   = (const float*)d_in[4];
  const float* A    = (const float*)d_in[5];
  const float* WB   = (const float*)d_in[6];
  const float* WC   = (const float*)d_in[7];
  const float* qd   = (const float*)d_in[8];
  const float* pd   = (const float*)d_in[9];
  const float* nfg  = (const float*)d_in[10];
  const float* nfb  = (const float*)d_in[11];
  const float* W1   = (const float*)d_in[12];
  const float* b1   = (const float*)d_in[13];
  const float* W2   = (const float*)d_in[14];
  const float* b2   = (const float*)d_in[15];

  float* ws = (float*)d_ws;
  float* hnbuf = ws;                          // NTOK*D
  float* delta = ws + 4194304;                // NTOK
  float* Bm    = delta + NTOK;                // NTOK*NX
  float* Cm    = Bm + NTOK * NX;              // NTOK*NX
  float* muv   = Cm + NTOK * NX;              // NTOK
  float* irsv  = muv + NTOK;                  // NTOK
  float* Tbuf  = irsv + NTOK;                 // 512
  float* At    = Tbuf + NBATCH * NCH;         // 4096
  float* Wbct  = At + D * NX;                 // 8192
  float* EX    = Wbct + D * 32;               // 512*4096 = 2M floats
  // bf16 fragment-packed MLP weights (hi/lo): 147456 ushorts = 288 KB
  unsigned short* W1fh = (unsigned short*)(EX + 2097152);  // 65536
  unsigned short* W1fl = W1fh + 65536;                     // 65536
  unsigned short* W2fh = W1fl + 65536;                     // 8192
  unsigned short* W2fl = W2fh + 8192;                      // 8192

  k0_prep<<<336, 256, 0, stream>>>(A, WB, WC, W1, W2, At, Wbct,
                                   W1fh, W1fl, W2fh, W2fl);
  k1a_front<<<NTOK / 16, 256, 0, stream>>>(y, Win, bin_, ng, nb, Wbct,
                                           qd, pd, hnbuf, delta, Bm, Cm,
                                           muv, irsv);
  k1s_scan<<<NTOK / 32, 256, 0, stream>>>(hnbuf, delta, Bm, At, EX, Tbuf);
  k2b_chunkscan<<<NBATCH * 64, 64, 0, stream>>>(At, Tbuf, EX);
  k2cd_scan_mlp<<<NTOK / 32, 256, 0, stream>>>(hnbuf, delta, Bm, Cm, At, EX,
                                               muv, irsv, ng, nb, nfg, nfb,
                                               W1fh, W1fl, W2fh, W2fl,
                                               b1, b2, (float*)d_out);
}

// Round 4
// 210.192 us; speedup vs baseline: 1.3854x; 1.3854x over previous
//
#include <hip/hip_runtime.h>
#include <math.h>

#define D 256
#define NX 16
#define L 2048
#define NBATCH 8
#define NTOK (NBATCH * L)
#define CL 32
#define NCH (L / CL)  // 64
#define LOG2E 1.44269504088896340736f

typedef float f32x4 __attribute__((ext_vector_type(4)));
// Fragment type for mfma_f32_16x16x32_bf16 on gfx950: 8 bf16 as 8 shorts.
typedef short bf16x8 __attribute__((ext_vector_type(8)));

// round-to-nearest-even f32 -> bf16 (as ushort bits)
__device__ __forceinline__ unsigned short f2bf(float x) {
  unsigned u = __float_as_uint(x);
  u = u + 0x7fffu + ((u >> 16) & 1u);
  return (unsigned short)(u >> 16);
}
__device__ __forceinline__ float bf2f(unsigned short h) {
  return __uint_as_float(((unsigned)h) << 16);
}

// ---------------- K0: At/Wbct prep + W1/W2 hi-lo bf16 fragment packing ------
// Fragment K-enumeration shared by A and B operands: element j of lane l
// covers k = s*32 + 8*(l>>4) + j; 16-dim = lane&15. Valid for any HW k-map.
__global__ __launch_bounds__(256) void k0_prep(const float* __restrict__ A,
                                               const float* __restrict__ WB,
                                               const float* __restrict__ WC,
                                               const float* __restrict__ W1,
                                               const float* __restrict__ W2,
                                               float* __restrict__ At,
                                               float* __restrict__ Wbct,
                                               unsigned short* __restrict__ W1fh,
                                               unsigned short* __restrict__ W1fl,
                                               unsigned short* __restrict__ W2fh,
                                               unsigned short* __restrict__ W2fl) {
  int i = blockIdx.x * 256 + threadIdx.x;  // 86016 total
  if (i < 4096) {
    int d = i >> 4, n = i & 15;
    At[n * D + d] = A[i] * LOG2E;
  } else if (i < 12288) {
    int j = i - 4096;  // 8192
    int d = j >> 5, c = j & 31;
    Wbct[j] = (c < 16) ? WB[c * D + d] : WC[(c - 16) * D + d];
  } else if (i < 77824) {
    // W1 frags: e = ((s*16 + t)*64 + l)*8 + j ; 65536 elems
    int e = i - 12288;
    int j = e & 7, l = (e >> 3) & 63, tt = (e >> 9) & 15, s = e >> 13;
    int k = s * 32 + ((l >> 4) << 3) + j;
    int n = tt * 16 + (l & 15);
    float x = W1[k * 256 + n];
    unsigned short h = f2bf(x);
    W1fh[e] = h;
    W1fl[e] = f2bf(x - bf2f(h));
  } else {
    // W2 frags: e = ((s*2 + t)*64 + l)*8 + j ; 8192 elems
    int e = i - 77824;
    int j = e & 7, l = (e >> 3) & 63, tt = (e >> 9) & 1, s = e >> 10;
    int k = s * 32 + ((l >> 4) << 3) + j;
    int n = tt * 16 + (l & 15);
    float x = W2[k * 32 + n];
    unsigned short h = f2bf(x);
    W2fh[e] = h;
    W2fl[e] = f2bf(x - bf2f(h));
  }
}

// ---------------- K1A: front end + LOCAL CHUNK SCAN fused ------------------
// 32 tok/block, grid 512. Register-lean restructure: phase A in 4 token-pairs
// (acc = 2 float4), restrained unrolls -> fits 128-VGPR cap WITHOUT spills.
// LDS 39.9 KB + cap -> 4 blocks/CU = 16 waves/CU (2x round-2 occupancy).
__global__ __launch_bounds__(256, 4) void k1a_front_scan(
    const float* __restrict__ y, const float* __restrict__ Win,
    const float* __restrict__ bin_, const float* __restrict__ ng,
    const float* __restrict__ nb, const float* __restrict__ Wbct,
    const float* __restrict__ qd, const float* __restrict__ pd,
    const float* __restrict__ At,
    float* __restrict__ hn, float* __restrict__ delta,
    float* __restrict__ Bm, float* __restrict__ Cm,
    float* __restrict__ muv, float* __restrict__ irsv,
    float* __restrict__ EX, float* __restrict__ T) {
  __shared__ float sy[32][32];
  __shared__ float sh[32][260];   // hn tile, pitch 260
  __shared__ float sB[32][NX];
  __shared__ float sdelta[32];
  int t = threadIdx.x;
  int tok0 = blockIdx.x * 32;     // blockIdx.x == global chunk index b*NCH+ch
  {
    const float4* src = (const float4*)(y + (size_t)tok0 * 32);
    ((float4*)sy)[t] = src[t];
  }
  __syncthreads();
  int dcol = t & 63;
  int jrow = t >> 6;
  int d4 = dcol * 4;
  float4 bv = ((const float4*)bin_)[dcol];
  float4 g4 = ((const float4*)ng)[dcol];
  float4 nb4 = ((const float4*)nb)[dcol];
  float4 q4 = ((const float4*)qd)[dcol];
  float pd0 = pd[0];
  const float4* Win4 = (const float4*)Win;
  // Phase A in 4 token-pairs: low register pressure (acc = 8 VGPRs).
  for (int g = 0; g < 4; ++g) {
    int j0 = jrow * 8 + g * 2;
    float4 acc0 = bv, acc1 = bv;
    #pragma unroll 4
    for (int k = 0; k < 32; ++k) {
      float4 wv = Win4[k * 64 + dcol];  // L1-resident after first pass
      float a0 = sy[j0][k];             // wave-uniform broadcast
      float a1 = sy[j0 + 1][k];
      acc0.x = fmaf(a0, wv.x, acc0.x); acc1.x = fmaf(a1, wv.x, acc1.x);
      acc0.y = fmaf(a0, wv.y, acc0.y); acc1.y = fmaf(a1, wv.y, acc1.y);
      acc0.z = fmaf(a0, wv.z, acc0.z); acc1.z = fmaf(a1, wv.z, acc1.z);
      acc0.w = fmaf(a0, wv.w, acc0.w); acc1.w = fmaf(a1, wv.w, acc1.w);
    }
    #pragma unroll
    for (int p = 0; p < 2; ++p) {
      int j = j0 + p;
      int tok = tok0 + j;
      float4 a = (p == 0) ? acc0 : acc1;
      float s1 = a.x + a.y + a.z + a.w;
      float s2 = a.x * a.x + a.y * a.y + a.z * a.z + a.w * a.w;
      #pragma unroll
      for (int off = 1; off < 64; off <<= 1) {
        s1 += __shfl_xor(s1, off);
        s2 += __shfl_xor(s2, off);
      }
      float mu = s1 * (1.f / D);
      float var = s2 * (1.f / D) - mu * mu;
      float rstd = rsqrtf(var + 1e-5f);
      if (dcol == 0) { muv[tok] = mu; irsv[tok] = sqrtf(var + 1e-5f); }
      float4 v4;
      v4.x = (a.x - mu) * rstd * g4.x + nb4.x;
      v4.y = (a.y - mu) * rstd * g4.y + nb4.y;
      v4.z = (a.z - mu) * rstd * g4.z + nb4.z;
      v4.w = (a.w - mu) * rstd * g4.w + nb4.w;
      ((float4*)(hn + (size_t)tok * D))[dcol] = v4;
      *(float4*)&sh[j][d4] = v4;
      float dd = v4.x * q4.x + v4.y * q4.y + v4.z * q4.z + v4.w * q4.w;
      #pragma unroll
      for (int off = 1; off < 64; off <<= 1) dd += __shfl_xor(dd, off);
      if (dcol == 0) {
        float xx = pd0 + dd;
        float dv = (xx > 20.f) ? xx : log1pf(expf(xx));
        delta[tok] = dv;
        sdelta[j] = dv;
      }
    }
  }
  __syncthreads();
  // chunk delta total (wave 0, lanes 0..31)
  if (t < 32) {
    float v = sdelta[t];
    #pragma unroll
    for (int off = 1; off < 32; off <<= 1) v += __shfl_xor(v, off);
    if (t == 0) T[blockIdx.x] = v;
  }
  // Phase C: [Bm|Cm] = sh @ Wbct; keep B columns in sB for the scan
  int col4 = t & 7;
  int j = t >> 3;
  const float4* W4 = (const float4*)Wbct;
  float4 o = make_float4(0.f, 0.f, 0.f, 0.f);
  #pragma unroll 4
  for (int d = 0; d < 256; ++d) {
    float av = sh[j][d];
    float4 w = W4[d * 8 + col4];
    o.x = fmaf(av, w.x, o.x);
    o.y = fmaf(av, w.y, o.y);
    o.z = fmaf(av, w.z, o.z);
    o.w = fmaf(av, w.w, o.w);
  }
  int tokj = tok0 + j;
  if (col4 < 4) {
    ((float4*)(Bm + (size_t)tokj * NX))[col4] = o;
    *(float4*)&sB[j][col4 * 4] = o;
  } else {
    ((float4*)(Cm + (size_t)tokj * NX))[col4 - 4] = o;
  }
  __syncthreads();
  // Scan phase: thread = d, state x[16] in regs, zero init
  float a16[16];
  #pragma unroll
  for (int n = 0; n < 16; ++n) a16[n] = At[n * D + t];
  float x16[16];
  #pragma unroll
  for (int n = 0; n < 16; ++n) x16[n] = 0.f;
  for (int lo = 0; lo < CL; ++lo) {
    float dlt = sdelta[lo];
    float du = dlt * sh[lo][t];
    #pragma unroll
    for (int n = 0; n < 16; ++n)
      x16[n] = fmaf(exp2f(dlt * a16[n]), x16[n], du * sB[lo][n]);
  }
  size_t exbase = (size_t)blockIdx.x * (NX * D) + t;
  #pragma unroll
  for (int n = 0; n < 16; ++n) EX[exbase + n * D] = x16[n];
}

// ---------------- K2b: chunk-level scan, 64-thr blocks (all CUs busy) ------
__global__ __launch_bounds__(64) void k2b_chunkscan(
    const float* __restrict__ At, const float* __restrict__ T,
    float* __restrict__ EX) {
  __shared__ float sT[NCH];
  int b = blockIdx.x >> 6;
  int rem = ((blockIdx.x & 63) << 6) | threadIdx.x;  // n*D + d
  sT[threadIdx.x] = T[b * NCH + threadIdx.x];
  __syncthreads();
  float A2 = At[rem];  // already *LOG2E
  size_t base = ((size_t)b << 18) + rem;
  float eq[4];
  #pragma unroll
  for (int j = 0; j < 4; ++j) eq[j] = EX[base + ((size_t)j << 12)];
  float x = 0.f;
  #pragma unroll 4
  for (int c = 0; c < NCH; ++c) {
    float e = eq[c & 3];
    if (c + 4 < NCH) eq[c & 3] = EX[base + ((size_t)(c + 4) << 12)];
    EX[base + ((size_t)c << 12)] = x;
    x = fmaf(exp2f(sT[c] * A2), x, e);
  }
}

__device__ __forceinline__ float gelu_exact(float x) {
  return 0.5f * x * (1.f + erff(x * 0.70710678118654752440f));
}

// ---------------- K2cd: fixup scan + h recon + LN2 + MFMA MLP ---------------
// bf16 hi/lo split MFMA, FULL 4-term (Ah*Bh + Al*Bh + Ah*Bl + Al*Bl):
// residual ~2^-18 rel. XOR-swizzled LDS A-tiles; W1/W2 fragments pre-packed
// (k0) with the same K-enumeration as the A-frag reads.
__global__ __launch_bounds__(256) void k2cd_scan_mlp(
    const float* __restrict__ hn, const float* __restrict__ delta,
    const float* __restrict__ Bm, const float* __restrict__ Cm,
    const float* __restrict__ At, const float* __restrict__ EX,
    const float* __restrict__ muv, const float* __restrict__ irsv,
    const float* __restrict__ ng, const float* __restrict__ nb,
    const float* __restrict__ nfg, const float* __restrict__ nfb,
    const unsigned short* __restrict__ W1fh, const unsigned short* __restrict__ W1fl,
    const unsigned short* __restrict__ W2fh, const unsigned short* __restrict__ W2fl,
    const float* __restrict__ b1, const float* __restrict__ b2,
    float* __restrict__ out) {
  __shared__ float s_az[32 * 260];                       // scan output (pre-LN2)
  __shared__ __align__(16) unsigned short sAh[32 * 256]; // bf16 hi (a-tile, then z)
  __shared__ __align__(16) unsigned short sAl[32 * 256]; // bf16 lo
  __shared__ float sB[32][NX];
  __shared__ float sC[32][NX];
  __shared__ float sdelta[32];
  __shared__ float smu[32];
  __shared__ float sirs[32];
  int t = threadIdx.x;
  int tok0 = blockIdx.x * 32;  // blockIdx.x == global chunk index
  size_t tokbase = (size_t)tok0;
  if (t < 32) {
    sdelta[t] = delta[tokbase + t];
    smu[t] = muv[tokbase + t];
    sirs[t] = irsv[tokbase + t];
  }
  for (int i = t; i < 32 * NX; i += 256) {
    ((float*)sB)[i] = Bm[tokbase * NX + i];
    ((float*)sC)[i] = Cm[tokbase * NX + i];
  }
  float a16[16], x16[16];
  size_t exbase = (size_t)blockIdx.x * (NX * D) + t;
  #pragma unroll
  for (int n = 0; n < 16; ++n) {
    a16[n] = At[n * D + t];
    x16[n] = EX[exbase + n * D];
  }
  float nb_d = nb[t];
  float invg = 1.0f / ng[t];
  __syncthreads();
  // scan with true entering state; hn read straight from global (used once)
  for (int lo = 0; lo < CL; ++lo) {
    float hv = hn[(tokbase + lo) * D + t];  // coalesced 1 KB/wave
    float dlt = sdelta[lo];
    float du = dlt * hv;
    float p = 0.f;
    #pragma unroll
    for (int n = 0; n < 16; ++n) {
      x16[n] = fmaf(exp2f(dlt * a16[n]), x16[n], du * sB[lo][n]);
      p = fmaf(x16[n], sC[lo][n], p);
    }
    float h = fmaf((hv - nb_d) * invg, sirs[lo], smu[lo]);
    s_az[lo * 260 + t] = h + p;  // final pre-LN2 value
  }
  __syncthreads();
  // LN2 (wave w owns tokens w*8..+7) -> bf16 hi/lo A-tile, XOR-swizzled
  int dcol = t & 63, jrow = t >> 6;
  int d4 = dcol * 4, j8 = jrow * 8;
  {
    float4 g4 = ((const float4*)nfg)[dcol];
    float4 b4 = ((const float4*)nfb)[dcol];
    for (int jj = 0; jj < 8; ++jj) {
      int lo = j8 + jj;
      float4 v = *(float4*)&s_az[lo * 260 + d4];
      float s1 = v.x + v.y + v.z + v.w;
      float s2 = v.x * v.x + v.y * v.y + v.z * v.z + v.w * v.w;
      #pragma unroll
      for (int off = 1; off < 64; off <<= 1) {
        s1 += __shfl_xor(s1, off);
        s2 += __shfl_xor(s2, off);
      }
      float mu2 = s1 * (1.f / D);
      float var2 = s2 * (1.f / D) - mu2 * mu2;
      float rstd2 = rsqrtf(var2 + 1e-5f);
      float4 o;
      o.x = (v.x - mu2) * rstd2 * g4.x + b4.x;
      o.y = (v.y - mu2) * rstd2 * g4.y + b4.y;
      o.z = (v.z - mu2) * rstd2 * g4.z + b4.z;
      o.w = (v.w - mu2) * rstd2 * g4.w + b4.w;
      unsigned short h0 = f2bf(o.x), h1 = f2bf(o.y), h2 = f2bf(o.z), h3 = f2bf(o.w);
      unsigned short q0 = f2bf(o.x - bf2f(h0));
      unsigned short q1 = f2bf(o.y - bf2f(h1));
      unsigned short q2 = f2bf(o.z - bf2f(h2));
      unsigned short q3 = f2bf(o.w - bf2f(h3));
      unsigned off16 = ((unsigned)(d4 * 2)) ^ ((unsigned)(lo & 7) << 4);
      uint2 hv2, lv2;
      hv2.x = (unsigned)h0 | ((unsigned)h1 << 16);
      hv2.y = (unsigned)h2 | ((unsigned)h3 << 16);
      lv2.x = (unsigned)q0 | ((unsigned)q1 << 16);
      lv2.y = (unsigned)q2 | ((unsigned)q3 << 16);
      *(uint2*)((char*)sAh + lo * 512 + off16) = hv2;
      *(uint2*)((char*)sAl + lo * 512 + off16) = lv2;
    }
  }
  __syncthreads();
  // ---- GEMM1: (32x256) @ W1 (256x256), wave w owns cols [w*64, w*64+64) ----
  int l = t & 63, w = t >> 6;
  const bf16x8* B1h = (const bf16x8*)W1fh;
  const bf16x8* B1l = (const bf16x8*)W1fl;
  f32x4 acc[2][4];
  #pragma unroll
  for (int m = 0; m < 2; ++m)
    #pragma unroll
    for (int n = 0; n < 4; ++n) {
      f32x4 z4 = {0.f, 0.f, 0.f, 0.f};
      acc[m][n] = z4;
    }
  #pragma unroll 2
  for (int s = 0; s < 8; ++s) {
    bf16x8 ah[2], al[2];
    #pragma unroll
    for (int m = 0; m < 2; ++m) {
      int row = m * 16 + (l & 15);
      unsigned off16 = ((unsigned)(s * 64 + ((l >> 4) << 4))) ^ ((unsigned)(row & 7) << 4);
      ah[m] = *(const bf16x8*)((const char*)sAh + row * 512 + off16);
      al[m] = *(const bf16x8*)((const char*)sAl + row * 512 + off16);
    }
    #pragma unroll
    for (int n = 0; n < 4; ++n) {
      int bi = (s * 16 + w * 4 + n) * 64 + l;
      bf16x8 bh = B1h[bi];
      bf16x8 bl = B1l[bi];
      #pragma unroll
      for (int m = 0; m < 2; ++m) {
        acc[m][n] = __builtin_amdgcn_mfma_f32_16x16x32_bf16(ah[m], bh, acc[m][n], 0, 0, 0);
        acc[m][n] = __builtin_amdgcn_mfma_f32_16x16x32_bf16(al[m], bh, acc[m][n], 0, 0, 0);
        acc[m][n] = __builtin_amdgcn_mfma_f32_16x16x32_bf16(ah[m], bl, acc[m][n], 0, 0, 0);
        acc[m][n] = __builtin_amdgcn_mfma_f32_16x16x32_bf16(al[m], bl, acc[m][n], 0, 0, 0);
      }
    }
  }
  __syncthreads();  // all A-tile reads done; sAh/sAl now reused for z
  // ---- b1 + gelu + convert -> z (bf16 hi/lo) back into sAh/sAl ----
  #pragma unroll
  for (int n = 0; n < 4; ++n) {
    int colz = w * 64 + n * 16 + (l & 15);
    float b1v = b1[colz];
    #pragma unroll
    for (int m = 0; m < 2; ++m) {
      #pragma unroll
      for (int r = 0; r < 4; ++r) {
        int row = m * 16 + ((l >> 4) << 2) + r;  // C/D: row=(lane>>4)*4+reg
        float zv = gelu_exact(acc[m][n][r] + b1v);
        unsigned short zh = f2bf(zv);
        unsigned short zl = f2bf(zv - bf2f(zh));
        unsigned off16 = ((unsigned)(colz * 2)) ^ ((unsigned)(row & 7) << 4);
        *(unsigned short*)((char*)sAh + row * 512 + off16) = zh;
        *(unsigned short*)((char*)sAl + row * 512 + off16) = zl;
      }
    }
  }
  __syncthreads();
  // ---- GEMM2: z (32x256) @ W2 (256x32); wave w -> (mw=w>>1, nw=w&1) ----
  int mw = w >> 1, nw = w & 1;
  const bf16x8* B2h = (const bf16x8*)W2fh;
  const bf16x8* B2l = (const bf16x8*)W2fl;
  f32x4 acc2 = {0.f, 0.f, 0.f, 0.f};
  #pragma unroll 2
  for (int s = 0; s < 8; ++s) {
    int row = mw * 16 + (l & 15);
    unsigned off16 = ((unsigned)(s * 64 + ((l >> 4) << 4))) ^ ((unsigned)(row & 7) << 4);
    bf16x8 zh8 = *(const bf16x8*)((const char*)sAh + row * 512 + off16);
    bf16x8 zl8 = *(const bf16x8*)((const char*)sAl + row * 512 + off16);
    int bi = (s * 2 + nw) * 64 + l;
    bf16x8 bh = B2h[bi];
    bf16x8 bl = B2l[bi];
    acc2 = __builtin_amdgcn_mfma_f32_16x16x32_bf16(zh8, bh, acc2, 0, 0, 0);
    acc2 = __builtin_amdgcn_mfma_f32_16x16x32_bf16(zl8, bh, acc2, 0, 0, 0);
    acc2 = __builtin_amdgcn_mfma_f32_16x16x32_bf16(zh8, bl, acc2, 0, 0, 0);
    acc2 = __builtin_amdgcn_mfma_f32_16x16x32_bf16(zl8, bl, acc2, 0, 0, 0);
  }
  int colo = nw * 16 + (l & 15);
  float b2v = b2[colo];
  #pragma unroll
  for (int r = 0; r < 4; ++r) {
    int row = mw * 16 + ((l >> 4) << 2) + r;
    out[(size_t)(tok0 + row) * 32 + colo] = acc2[r] + b2v;
  }
}

extern "C" void kernel_launch(void* const* d_in, const int* in_sizes, int n_in,
                              void* d_out, int out_size, void* d_ws, size_t ws_size,
                              hipStream_t stream) {
  const float* y    = (const float*)d_in[0];
  const float* Win  = (const float*)d_in[1];
  const float* bin_ = (const float*)d_in[2];
  const float* ng   = (const float*)d_in[3];
  const float* nb   = (const float*)d_in[4];
  const float* A    = (const float*)d_in[5];
  const float* WB   = (const float*)d_in[6];
  const float* WC   = (const float*)d_in[7];
  const float* qd   = (const float*)d_in[8];
  const float* pd   = (const float*)d_in[9];
  const float* nfg  = (const float*)d_in[10];
  const float* nfb  = (const float*)d_in[11];
  const float* W1   = (const float*)d_in[12];
  const float* b1   = (const float*)d_in[13];
  const float* W2   = (const float*)d_in[14];
  const float* b2   = (const float*)d_in[15];

  float* ws = (float*)d_ws;
  float* hnbuf = ws;                          // NTOK*D
  float* delta = ws + 4194304;                // NTOK
  float* Bm    = delta + NTOK;                // NTOK*NX
  float* Cm    = Bm + NTOK * NX;              // NTOK*NX
  float* muv   = Cm + NTOK * NX;              // NTOK
  float* irsv  = muv + NTOK;                  // NTOK
  float* Tbuf  = irsv + NTOK;                 // 512
  float* At    = Tbuf + NBATCH * NCH;         // 4096
  float* Wbct  = At + D * NX;                 // 8192
  float* EX    = Wbct + D * 32;               // 512*4096 = 2M floats
  // bf16 fragment-packed MLP weights (hi/lo): 147456 ushorts = 288 KB
  unsigned short* W1fh = (unsigned short*)(EX + 2097152);  // 65536
  unsigned short* W1fl = W1fh + 65536;                     // 65536
  unsigned short* W2fh = W1fl + 65536;                     // 8192
  unsigned short* W2fl = W2fh + 8192;                      // 8192

  k0_prep<<<336, 256, 0, stream>>>(A, WB, WC, W1, W2, At, Wbct,
                                   W1fh, W1fl, W2fh, W2fl);
  k1a_front_scan<<<NTOK / 32, 256, 0, stream>>>(y, Win, bin_, ng, nb, Wbct,
                                                qd, pd, At, hnbuf, delta, Bm,
                                                Cm, muv, irsv, EX, Tbuf);
  k2b_chunkscan<<<NBATCH * 64, 64, 0, stream>>>(At, Tbuf, EX);
  k2cd_scan_mlp<<<NTOK / 32, 256, 0, stream>>>(hnbuf, delta, Bm, Cm, At, EX,
                                               muv, irsv, ng, nb, nfg, nfb,
                                               W1fh, W1fl, W2fh, W2fl,
                                               b1, b2, (float*)d_out);
}

// Round 5
// 199.440 us; speedup vs baseline: 1.4601x; 1.0539x over previous
//
#include <hip/hip_runtime.h>
#include <math.h>

#define D 256
#define NX 16
#define L 2048
#define NBATCH 8
#define NTOK (NBATCH * L)
#define CL 32
#define NCH (L / CL)  // 64
#define LOG2E 1.44269504088896340736f

typedef float f32x4 __attribute__((ext_vector_type(4)));
// Fragment type for mfma_f32_16x16x32_bf16 on gfx950: 8 bf16 as 8 shorts.
typedef short bf16x8 __attribute__((ext_vector_type(8)));

// round-to-nearest-even f32 -> bf16 (as ushort bits)
__device__ __forceinline__ unsigned short f2bf(float x) {
  unsigned u = __float_as_uint(x);
  u = u + 0x7fffu + ((u >> 16) & 1u);
  return (unsigned short)(u >> 16);
}
__device__ __forceinline__ float bf2f(unsigned short h) {
  return __uint_as_float(((unsigned)h) << 16);
}

// ---------------- K0: At/Wbct prep + W1/W2 hi-lo bf16 fragment packing ------
// Fragment K-enumeration shared by A and B operands: element j of lane l
// covers k = s*32 + 8*(l>>4) + j; 16-dim = lane&15. Valid for any HW k-map.
__global__ __launch_bounds__(256) void k0_prep(const float* __restrict__ A,
                                               const float* __restrict__ WB,
                                               const float* __restrict__ WC,
                                               const float* __restrict__ W1,
                                               const float* __restrict__ W2,
                                               float* __restrict__ At,
                                               float* __restrict__ Wbct,
                                               unsigned short* __restrict__ W1fh,
                                               unsigned short* __restrict__ W1fl,
                                               unsigned short* __restrict__ W2fh,
                                               unsigned short* __restrict__ W2fl) {
  int i = blockIdx.x * 256 + threadIdx.x;  // 86016 total
  if (i < 4096) {
    int d = i >> 4, n = i & 15;
    At[n * D + d] = A[i] * LOG2E;
  } else if (i < 12288) {
    int j = i - 4096;  // 8192
    int d = j >> 5, c = j & 31;
    Wbct[j] = (c < 16) ? WB[c * D + d] : WC[(c - 16) * D + d];
  } else if (i < 77824) {
    // W1 frags: e = ((s*16 + t)*64 + l)*8 + j ; 65536 elems
    int e = i - 12288;
    int j = e & 7, l = (e >> 3) & 63, tt = (e >> 9) & 15, s = e >> 13;
    int k = s * 32 + ((l >> 4) << 3) + j;
    int n = tt * 16 + (l & 15);
    float x = W1[k * 256 + n];
    unsigned short h = f2bf(x);
    W1fh[e] = h;
    W1fl[e] = f2bf(x - bf2f(h));
  } else {
    // W2 frags: e = ((s*2 + t)*64 + l)*8 + j ; 8192 elems
    int e = i - 77824;
    int j = e & 7, l = (e >> 3) & 63, tt = (e >> 9) & 1, s = e >> 10;
    int k = s * 32 + ((l >> 4) << 3) + j;
    int n = tt * 16 + (l & 15);
    float x = W2[k * 32 + n];
    unsigned short h = f2bf(x);
    W2fh[e] = h;
    W2fl[e] = f2bf(x - bf2f(h));
  }
}

// ---------------- K1A: front end + LOCAL CHUNK SCAN, 512 threads/block -----
// Grid 512 (one block per 32-token chunk), 8 waves/block -> 16 waves/CU at
// 2 blocks/CU (LDS 47.4 KB). Phase A: 4 tokens/wave in 2 pairs. Phase C:
// K split in 2 halves + LDS combine. Scan: n-channels split across thread
// halves (x8 regs/thread) — channels are independent recurrences.
__global__ __launch_bounds__(512, 4) void k1a_front_scan(
    const float* __restrict__ y, const float* __restrict__ Win,
    const float* __restrict__ bin_, const float* __restrict__ ng,
    const float* __restrict__ nb, const float* __restrict__ Wbct,
    const float* __restrict__ qd, const float* __restrict__ pd,
    const float* __restrict__ At,
    float* __restrict__ hn, float* __restrict__ delta,
    float* __restrict__ Bm, float* __restrict__ Cm,
    float* __restrict__ muv, float* __restrict__ irsv,
    float* __restrict__ EX, float* __restrict__ T) {
  __shared__ float sy[32][32];
  __shared__ float sh[32][260];      // hn tile, pitch 260
  __shared__ float sB[32][NX];
  __shared__ float sdelta[32];
  __shared__ float sph[2 * 32 * 32]; // phase-C half-K partials
  int t = threadIdx.x;
  int tok0 = blockIdx.x * 32;        // blockIdx.x == global chunk index
  if (t < 256) {
    const float4* src = (const float4*)(y + (size_t)tok0 * 32);
    ((float4*)sy)[t] = src[t];
  }
  __syncthreads();
  int dcol = t & 63;
  int jrow = t >> 6;                 // wave id 0..7 -> tokens jrow*4..+3
  int d4 = dcol * 4;
  float4 bv = ((const float4*)bin_)[dcol];
  float4 g4 = ((const float4*)ng)[dcol];
  float4 nb4 = ((const float4*)nb)[dcol];
  float4 q4 = ((const float4*)qd)[dcol];
  float pd0 = pd[0];
  const float4* Win4 = (const float4*)Win;
  // Phase A: 2 token-pairs per wave (acc = 8 VGPRs live).
  for (int g = 0; g < 2; ++g) {
    int j0 = jrow * 4 + g * 2;
    float4 acc0 = bv, acc1 = bv;
    #pragma unroll 4
    for (int k = 0; k < 32; ++k) {
      float4 wv = Win4[k * 64 + dcol];  // L1/L2-resident
      float a0 = sy[j0][k];             // wave-uniform broadcast
      float a1 = sy[j0 + 1][k];
      acc0.x = fmaf(a0, wv.x, acc0.x); acc1.x = fmaf(a1, wv.x, acc1.x);
      acc0.y = fmaf(a0, wv.y, acc0.y); acc1.y = fmaf(a1, wv.y, acc1.y);
      acc0.z = fmaf(a0, wv.z, acc0.z); acc1.z = fmaf(a1, wv.z, acc1.z);
      acc0.w = fmaf(a0, wv.w, acc0.w); acc1.w = fmaf(a1, wv.w, acc1.w);
    }
    #pragma unroll
    for (int p = 0; p < 2; ++p) {
      int j = j0 + p;
      int tok = tok0 + j;
      float4 a = (p == 0) ? acc0 : acc1;
      float s1 = a.x + a.y + a.z + a.w;
      float s2 = a.x * a.x + a.y * a.y + a.z * a.z + a.w * a.w;
      #pragma unroll
      for (int off = 1; off < 64; off <<= 1) {
        s1 += __shfl_xor(s1, off);
        s2 += __shfl_xor(s2, off);
      }
      float mu = s1 * (1.f / D);
      float var = s2 * (1.f / D) - mu * mu;
      float rstd = rsqrtf(var + 1e-5f);
      if (dcol == 0) { muv[tok] = mu; irsv[tok] = sqrtf(var + 1e-5f); }
      float4 v4;
      v4.x = (a.x - mu) * rstd * g4.x + nb4.x;
      v4.y = (a.y - mu) * rstd * g4.y + nb4.y;
      v4.z = (a.z - mu) * rstd * g4.z + nb4.z;
      v4.w = (a.w - mu) * rstd * g4.w + nb4.w;
      ((float4*)(hn + (size_t)tok * D))[dcol] = v4;
      *(float4*)&sh[j][d4] = v4;
      float dd = v4.x * q4.x + v4.y * q4.y + v4.z * q4.z + v4.w * q4.w;
      #pragma unroll
      for (int off = 1; off < 64; off <<= 1) dd += __shfl_xor(dd, off);
      if (dcol == 0) {
        float xx = pd0 + dd;
        float dv = (xx > 20.f) ? xx : log1pf(expf(xx));
        delta[tok] = dv;
        sdelta[j] = dv;
      }
    }
  }
  __syncthreads();
  // chunk delta total (wave 0, lanes 0..31)
  if (t < 32) {
    float v = sdelta[t];
    #pragma unroll
    for (int off = 1; off < 32; off <<= 1) v += __shfl_xor(v, off);
    if (t == 0) T[blockIdx.x] = v;
  }
  // Phase C: [Bm|Cm](32x32) = sh(32x256) @ Wbct(256x32); K split in 2 halves
  {
    int hk = t >> 8;            // 0/1
    int r = t & 255;
    int col4 = r & 7;
    int j = r >> 3;
    const float* shrow = &sh[j][hk * 128];
    const float4* W4 = (const float4*)Wbct + (size_t)hk * 128 * 8;
    float4 o = make_float4(0.f, 0.f, 0.f, 0.f);
    #pragma unroll 4
    for (int k = 0; k < 128; ++k) {
      float av = shrow[k];
      float4 wv = W4[k * 8 + col4];
      o.x = fmaf(av, wv.x, o.x);
      o.y = fmaf(av, wv.y, o.y);
      o.z = fmaf(av, wv.z, o.z);
      o.w = fmaf(av, wv.w, o.w);
    }
    *(float4*)&sph[((hk * 32 + j) << 5) + col4 * 4] = o;
  }
  __syncthreads();
  if (t < 256) {
    int j = t >> 3, cc = t & 7;
    float4 r0 = *(float4*)&sph[(j << 5) + cc * 4];
    float4 r1 = *(float4*)&sph[((32 + j) << 5) + cc * 4];
    float4 r;
    r.x = r0.x + r1.x; r.y = r0.y + r1.y;
    r.z = r0.z + r1.z; r.w = r0.w + r1.w;
    int tokj = tok0 + j;
    if (cc < 4) {
      ((float4*)(Bm + (size_t)tokj * NX))[cc] = r;
      *(float4*)&sB[j][cc * 4] = r;
    } else {
      ((float4*)(Cm + (size_t)tokj * NX))[cc - 4] = r;
    }
  }
  __syncthreads();
  // Scan: n-split across thread halves; thread = (half, d), x8 in regs.
  {
    int half = t >> 8;          // 0: n=0..7, 1: n=8..15
    int d = t & 255;
    float a8[8], x8[8];
    #pragma unroll
    for (int n = 0; n < 8; ++n) {
      a8[n] = At[(half * 8 + n) * D + d];
      x8[n] = 0.f;
    }
    for (int lo = 0; lo < CL; ++lo) {
      float dlt = sdelta[lo];
      float du = dlt * sh[lo][d];
      #pragma unroll
      for (int n = 0; n < 8; ++n)
        x8[n] = fmaf(exp2f(dlt * a8[n]), x8[n], du * sB[lo][half * 8 + n]);
    }
    size_t exbase = (size_t)blockIdx.x * (NX * D) + d;
    #pragma unroll
    for (int n = 0; n < 8; ++n) EX[exbase + (half * 8 + n) * D] = x8[n];
  }
}

// ---------------- K2b: chunk-level scan, 8-deep prefetch ring --------------
__global__ __launch_bounds__(64) void k2b_chunkscan(
    const float* __restrict__ At, const float* __restrict__ T,
    float* __restrict__ EX) {
  __shared__ float sT[NCH];
  int b = blockIdx.x >> 6;
  int rem = ((blockIdx.x & 63) << 6) | threadIdx.x;  // n*D + d
  sT[threadIdx.x] = T[b * NCH + threadIdx.x];
  __syncthreads();
  float A2 = At[rem];  // already *LOG2E
  size_t base = ((size_t)b << 18) + rem;
  float eq[8];
  #pragma unroll
  for (int j = 0; j < 8; ++j) eq[j] = EX[base + ((size_t)j << 12)];
  float x = 0.f;
  #pragma unroll 8
  for (int c = 0; c < NCH; ++c) {
    float e = eq[c & 7];
    if (c + 8 < NCH) eq[c & 7] = EX[base + ((size_t)(c + 8) << 12)];
    EX[base + ((size_t)c << 12)] = x;
    x = fmaf(exp2f(sT[c] * A2), x, e);
  }
}

__device__ __forceinline__ float gelu_exact(float x) {
  return 0.5f * x * (1.f + erff(x * 0.70710678118654752440f));
}

// ---------------- K2cd: fixup scan + h recon + LN2 + MFMA MLP ---------------
// bf16 hi/lo split MFMA, FULL 4-term (Ah*Bh + Al*Bh + Ah*Bl + Al*Bl):
// residual ~2^-18 rel. XOR-swizzled LDS A-tiles; W1/W2 fragments pre-packed
// (k0) with the same K-enumeration as the A-frag reads.
__global__ __launch_bounds__(256) void k2cd_scan_mlp(
    const float* __restrict__ hn, const float* __restrict__ delta,
    const float* __restrict__ Bm, const float* __restrict__ Cm,
    const float* __restrict__ At, const float* __restrict__ EX,
    const float* __restrict__ muv, const float* __restrict__ irsv,
    const float* __restrict__ ng, const float* __restrict__ nb,
    const float* __restrict__ nfg, const float* __restrict__ nfb,
    const unsigned short* __restrict__ W1fh, const unsigned short* __restrict__ W1fl,
    const unsigned short* __restrict__ W2fh, const unsigned short* __restrict__ W2fl,
    const float* __restrict__ b1, const float* __restrict__ b2,
    float* __restrict__ out) {
  __shared__ float s_az[32 * 260];                       // scan output (pre-LN2)
  __shared__ __align__(16) unsigned short sAh[32 * 256]; // bf16 hi (a-tile, then z)
  __shared__ __align__(16) unsigned short sAl[32 * 256]; // bf16 lo
  __shared__ float sB[32][NX];
  __shared__ float sC[32][NX];
  __shared__ float sdelta[32];
  __shared__ float smu[32];
  __shared__ float sirs[32];
  int t = threadIdx.x;
  int tok0 = blockIdx.x * 32;  // blockIdx.x == global chunk index
  size_t tokbase = (size_t)tok0;
  if (t < 32) {
    sdelta[t] = delta[tokbase + t];
    smu[t] = muv[tokbase + t];
    sirs[t] = irsv[tokbase + t];
  }
  for (int i = t; i < 32 * NX; i += 256) {
    ((float*)sB)[i] = Bm[tokbase * NX + i];
    ((float*)sC)[i] = Cm[tokbase * NX + i];
  }
  float a16[16], x16[16];
  size_t exbase = (size_t)blockIdx.x * (NX * D) + t;
  #pragma unroll
  for (int n = 0; n < 16; ++n) {
    a16[n] = At[n * D + t];
    x16[n] = EX[exbase + n * D];
  }
  float nb_d = nb[t];
  float invg = 1.0f / ng[t];
  __syncthreads();
  // scan with true entering state; hn read straight from global (used once)
  for (int lo = 0; lo < CL; ++lo) {
    float hv = hn[(tokbase + lo) * D + t];  // coalesced 1 KB/wave
    float dlt = sdelta[lo];
    float du = dlt * hv;
    float p = 0.f;
    #pragma unroll
    for (int n = 0; n < 16; ++n) {
      x16[n] = fmaf(exp2f(dlt * a16[n]), x16[n], du * sB[lo][n]);
      p = fmaf(x16[n], sC[lo][n], p);
    }
    float h = fmaf((hv - nb_d) * invg, sirs[lo], smu[lo]);
    s_az[lo * 260 + t] = h + p;  // final pre-LN2 value
  }
  __syncthreads();
  // LN2 (wave w owns tokens w*8..+7) -> bf16 hi/lo A-tile, XOR-swizzled
  int dcol = t & 63, jrow = t >> 6;
  int d4 = dcol * 4, j8 = jrow * 8;
  {
    float4 g4 = ((const float4*)nfg)[dcol];
    float4 b4 = ((const float4*)nfb)[dcol];
    for (int jj = 0; jj < 8; ++jj) {
      int lo = j8 + jj;
      float4 v = *(float4*)&s_az[lo * 260 + d4];
      float s1 = v.x + v.y + v.z + v.w;
      float s2 = v.x * v.x + v.y * v.y + v.z * v.z + v.w * v.w;
      #pragma unroll
      for (int off = 1; off < 64; off <<= 1) {
        s1 += __shfl_xor(s1, off);
        s2 += __shfl_xor(s2, off);
      }
      float mu2 = s1 * (1.f / D);
      float var2 = s2 * (1.f / D) - mu2 * mu2;
      float rstd2 = rsqrtf(var2 + 1e-5f);
      float4 o;
      o.x = (v.x - mu2) * rstd2 * g4.x + b4.x;
      o.y = (v.y - mu2) * rstd2 * g4.y + b4.y;
      o.z = (v.z - mu2) * rstd2 * g4.z + b4.z;
      o.w = (v.w - mu2) * rstd2 * g4.w + b4.w;
      unsigned short h0 = f2bf(o.x), h1 = f2bf(o.y), h2 = f2bf(o.z), h3 = f2bf(o.w);
      unsigned short q0 = f2bf(o.x - bf2f(h0));
      unsigned short q1 = f2bf(o.y - bf2f(h1));
      unsigned short q2 = f2bf(o.z - bf2f(h2));
      unsigned short q3 = f2bf(o.w - bf2f(h3));
      unsigned off16 = ((unsigned)(d4 * 2)) ^ ((unsigned)(lo & 7) << 4);
      uint2 hv2, lv2;
      hv2.x = (unsigned)h0 | ((unsigned)h1 << 16);
      hv2.y = (unsigned)h2 | ((unsigned)h3 << 16);
      lv2.x = (unsigned)q0 | ((unsigned)q1 << 16);
      lv2.y = (unsigned)q2 | ((unsigned)q3 << 16);
      *(uint2*)((char*)sAh + lo * 512 + off16) = hv2;
      *(uint2*)((char*)sAl + lo * 512 + off16) = lv2;
    }
  }
  __syncthreads();
  // ---- GEMM1: (32x256) @ W1 (256x256), wave w owns cols [w*64, w*64+64) ----
  int l = t & 63, w = t >> 6;
  const bf16x8* B1h = (const bf16x8*)W1fh;
  const bf16x8* B1l = (const bf16x8*)W1fl;
  f32x4 acc[2][4];
  #pragma unroll
  for (int m = 0; m < 2; ++m)
    #pragma unroll
    for (int n = 0; n < 4; ++n) {
      f32x4 z4 = {0.f, 0.f, 0.f, 0.f};
      acc[m][n] = z4;
    }
  #pragma unroll 2
  for (int s = 0; s < 8; ++s) {
    bf16x8 ah[2], al[2];
    #pragma unroll
    for (int m = 0; m < 2; ++m) {
      int row = m * 16 + (l & 15);
      unsigned off16 = ((unsigned)(s * 64 + ((l >> 4) << 4))) ^ ((unsigned)(row & 7) << 4);
      ah[m] = *(const bf16x8*)((const char*)sAh + row * 512 + off16);
      al[m] = *(const bf16x8*)((const char*)sAl + row * 512 + off16);
    }
    #pragma unroll
    for (int n = 0; n < 4; ++n) {
      int bi = (s * 16 + w * 4 + n) * 64 + l;
      bf16x8 bh = B1h[bi];
      bf16x8 bl = B1l[bi];
      #pragma unroll
      for (int m = 0; m < 2; ++m) {
        acc[m][n] = __builtin_amdgcn_mfma_f32_16x16x32_bf16(ah[m], bh, acc[m][n], 0, 0, 0);
        acc[m][n] = __builtin_amdgcn_mfma_f32_16x16x32_bf16(al[m], bh, acc[m][n], 0, 0, 0);
        acc[m][n] = __builtin_amdgcn_mfma_f32_16x16x32_bf16(ah[m], bl, acc[m][n], 0, 0, 0);
        acc[m][n] = __builtin_amdgcn_mfma_f32_16x16x32_bf16(al[m], bl, acc[m][n], 0, 0, 0);
      }
    }
  }
  __syncthreads();  // all A-tile reads done; sAh/sAl now reused for z
  // ---- b1 + gelu + convert -> z (bf16 hi/lo) back into sAh/sAl ----
  #pragma unroll
  for (int n = 0; n < 4; ++n) {
    int colz = w * 64 + n * 16 + (l & 15);
    float b1v = b1[colz];
    #pragma unroll
    for (int m = 0; m < 2; ++m) {
      #pragma unroll
      for (int r = 0; r < 4; ++r) {
        int row = m * 16 + ((l >> 4) << 2) + r;  // C/D: row=(lane>>4)*4+reg
        float zv = gelu_exact(acc[m][n][r] + b1v);
        unsigned short zh = f2bf(zv);
        unsigned short zl = f2bf(zv - bf2f(zh));
        unsigned off16 = ((unsigned)(colz * 2)) ^ ((unsigned)(row & 7) << 4);
        *(unsigned short*)((char*)sAh + row * 512 + off16) = zh;
        *(unsigned short*)((char*)sAl + row * 512 + off16) = zl;
      }
    }
  }
  __syncthreads();
  // ---- GEMM2: z (32x256) @ W2 (256x32); wave w -> (mw=w>>1, nw=w&1) ----
  int mw = w >> 1, nw = w & 1;
  const bf16x8* B2h = (const bf16x8*)W2fh;
  const bf16x8* B2l = (const bf16x8*)W2fl;
  f32x4 acc2 = {0.f, 0.f, 0.f, 0.f};
  #pragma unroll 2
  for (int s = 0; s < 8; ++s) {
    int row = mw * 16 + (l & 15);
    unsigned off16 = ((unsigned)(s * 64 + ((l >> 4) << 4))) ^ ((unsigned)(row & 7) << 4);
    bf16x8 zh8 = *(const bf16x8*)((const char*)sAh + row * 512 + off16);
    bf16x8 zl8 = *(const bf16x8*)((const char*)sAl + row * 512 + off16);
    int bi = (s * 2 + nw) * 64 + l;
    bf16x8 bh = B2h[bi];
    bf16x8 bl = B2l[bi];
    acc2 = __builtin_amdgcn_mfma_f32_16x16x32_bf16(zh8, bh, acc2, 0, 0, 0);
    acc2 = __builtin_amdgcn_mfma_f32_16x16x32_bf16(zl8, bh, acc2, 0, 0, 0);
    acc2 = __builtin_amdgcn_mfma_f32_16x16x32_bf16(zh8, bl, acc2, 0, 0, 0);
    acc2 = __builtin_amdgcn_mfma_f32_16x16x32_bf16(zl8, bl, acc2, 0, 0, 0);
  }
  int colo = nw * 16 + (l & 15);
  float b2v = b2[colo];
  #pragma unroll
  for (int r = 0; r < 4; ++r) {
    int row = mw * 16 + ((l >> 4) << 2) + r;
    out[(size_t)(tok0 + row) * 32 + colo] = acc2[r] + b2v;
  }
}

extern "C" void kernel_launch(void* const* d_in, const int* in_sizes, int n_in,
                              void* d_out, int out_size, void* d_ws, size_t ws_size,
                              hipStream_t stream) {
  const float* y    = (const float*)d_in[0];
  const float* Win  = (const float*)d_in[1];
  const float* bin_ = (const float*)d_in[2];
  const float* ng   = (const float*)d_in[3];
  const float* nb   = (const float*)d_in[4];
  const float* A    = (const float*)d_in[5];
  const float* WB   = (const float*)d_in[6];
  const float* WC   = (const float*)d_in[7];
  const float* qd   = (const float*)d_in[8];
  const float* pd   = (const float*)d_in[9];
  const float* nfg  = (const float*)d_in[10];
  const float* nfb  = (const float*)d_in[11];
  const float* W1   = (const float*)d_in[12];
  const float* b1   = (const float*)d_in[13];
  const float* W2   = (const float*)d_in[14];
  const float* b2   = (const float*)d_in[15];

  float* ws = (float*)d_ws;
  float* hnbuf = ws;                          // NTOK*D
  float* delta = ws + 4194304;                // NTOK
  float* Bm    = delta + NTOK;                // NTOK*NX
  float* Cm    = Bm + NTOK * NX;              // NTOK*NX
  float* muv   = Cm + NTOK * NX;              // NTOK
  float* irsv  = muv + NTOK;                  // NTOK
  float* Tbuf  = irsv + NTOK;                 // 512
  float* At    = Tbuf + NBATCH * NCH;         // 4096
  float* Wbct  = At + D * NX;                 // 8192
  float* EX    = Wbct + D * 32;               // 512*4096 = 2M floats
  // bf16 fragment-packed MLP weights (hi/lo): 147456 ushorts = 288 KB
  unsigned short* W1fh = (unsigned short*)(EX + 2097152);  // 65536
  unsigned short* W1fl = W1fh + 65536;                     // 65536
  unsigned short* W2fh = W1fl + 65536;                     // 8192
  unsigned short* W2fl = W2fh + 8192;                      // 8192

  k0_prep<<<336, 256, 0, stream>>>(A, WB, WC, W1, W2, At, Wbct,
                                   W1fh, W1fl, W2fh, W2fl);
  k1a_front_scan<<<NTOK / 32, 512, 0, stream>>>(y, Win, bin_, ng, nb, Wbct,
                                                qd, pd, At, hnbuf, delta, Bm,
                                                Cm, muv, irsv, EX, Tbuf);
  k2b_chunkscan<<<NBATCH * 64, 64, 0, stream>>>(At, Tbuf, EX);
  k2cd_scan_mlp<<<NTOK / 32, 256, 0, stream>>>(hnbuf, delta, Bm, Cm, At, EX,
                                               muv, irsv, ng, nb, nfg, nfb,
                                               W1fh, W1fl, W2fh, W2fl,
                                               b1, b2, (float*)d_out);
}

// Round 6
// 182.112 us; speedup vs baseline: 1.5991x; 1.0951x over previous
//
#include <hip/hip_runtime.h>
#include <math.h>

#define D 256
#define NX 16
#define L 2048
#define NBATCH 8
#define NTOK (NBATCH * L)
#define CL 32
#define NCH (L / CL)  // 64
#define LOG2E 1.44269504088896340736f

typedef float f32x4 __attribute__((ext_vector_type(4)));
// Fragment type for mfma_f32_16x16x32_bf16 on gfx950: 8 bf16 as 8 shorts.
typedef short bf16x8 __attribute__((ext_vector_type(8)));

// round-to-nearest-even f32 -> bf16 (as ushort bits)
__device__ __forceinline__ unsigned short f2bf(float x) {
  unsigned u = __float_as_uint(x);
  u = u + 0x7fffu + ((u >> 16) & 1u);
  return (unsigned short)(u >> 16);
}
__device__ __forceinline__ float bf2f(unsigned short h) {
  return __uint_as_float(((unsigned)h) << 16);
}

// ---------------- K0: At prep + ALL weight fragment packing (hi/lo bf16) ----
// Fragment K-enumeration shared by A and B operands: element j of lane l
// covers k = s*32 + 8*(l>>4) + j; 16-dim = lane&15. Valid for any HW k-map.
__global__ __launch_bounds__(256) void k0_prep(const float* __restrict__ A,
                                               const float* __restrict__ WB,
                                               const float* __restrict__ WC,
                                               const float* __restrict__ Win,
                                               const float* __restrict__ W1,
                                               const float* __restrict__ W2,
                                               float* __restrict__ At,
                                               unsigned short* __restrict__ W1fh,
                                               unsigned short* __restrict__ W1fl,
                                               unsigned short* __restrict__ W2fh,
                                               unsigned short* __restrict__ W2fl,
                                               unsigned short* __restrict__ Winfh,
                                               unsigned short* __restrict__ Winfl,
                                               unsigned short* __restrict__ Wbcfh,
                                               unsigned short* __restrict__ Wbcfl) {
  int i = blockIdx.x * 256 + threadIdx.x;  // 94208 total
  if (i < 4096) {
    int d = i >> 4, n = i & 15;
    At[n * D + d] = A[i] * LOG2E;
  } else if (i < 12288) {
    // Win frags (B of phase A, K=32): e = (tt*64 + l)*8 + j, tt=0..15
    int e = i - 4096;
    int j = e & 7, l = (e >> 3) & 63, tt = e >> 9;
    int k = ((l >> 4) << 3) + j;        // K=32, single K-step
    int n = tt * 16 + (l & 15);
    float x = Win[k * 256 + n];
    unsigned short h = f2bf(x);
    Winfh[e] = h;
    Winfl[e] = f2bf(x - bf2f(h));
  } else if (i < 20480) {
    // Wbct frags (B of phase C): e = ((s*2+tt)*64 + l)*8 + j
    int e = i - 12288;
    int j = e & 7, l = (e >> 3) & 63, q = e >> 9;  // q = s*2+tt
    int s = q >> 1, tt = q & 1;
    int k = s * 32 + ((l >> 4) << 3) + j;
    int n = tt * 16 + (l & 15);
    float x = (n < 16) ? WB[n * 256 + k] : WC[(n - 16) * 256 + k];
    unsigned short h = f2bf(x);
    Wbcfh[e] = h;
    Wbcfl[e] = f2bf(x - bf2f(h));
  } else if (i < 86016) {
    // W1 frags: e = ((s*16 + t)*64 + l)*8 + j ; 65536 elems
    int e = i - 20480;
    int j = e & 7, l = (e >> 3) & 63, tt = (e >> 9) & 15, s = e >> 13;
    int k = s * 32 + ((l >> 4) << 3) + j;
    int n = tt * 16 + (l & 15);
    float x = W1[k * 256 + n];
    unsigned short h = f2bf(x);
    W1fh[e] = h;
    W1fl[e] = f2bf(x - bf2f(h));
  } else {
    // W2 frags: e = ((s*2 + t)*64 + l)*8 + j ; 8192 elems
    int e = i - 86016;
    int j = e & 7, l = (e >> 3) & 63, tt = (e >> 9) & 1, s = e >> 10;
    int k = s * 32 + ((l >> 4) << 3) + j;
    int n = tt * 16 + (l & 15);
    float x = W2[k * 32 + n];
    unsigned short h = f2bf(x);
    W2fh[e] = h;
    W2fl[e] = f2bf(x - bf2f(h));
  }
}

// ---------------- K1A: MFMA front end + LOCAL CHUNK SCAN, 512 thr ----------
// Phase A: h = y@Win + bin via MFMA (wave w owns d-cols [w*32,w*32+32)).
// LN/delta via 16-lane shfl partials + LDS combine. Phase C: [Bm|Cm] =
// hn@Wbct via MFMA (waves 0-3; waves 4-7 copy hn->global concurrently).
// Scan: n-split halves as before. LDS ~73 KB -> 2 blocks/CU.
__global__ __launch_bounds__(512, 4) void k1a_front_scan(
    const float* __restrict__ y, const float* __restrict__ bin_,
    const float* __restrict__ ng, const float* __restrict__ nb,
    const float* __restrict__ qd, const float* __restrict__ pd,
    const float* __restrict__ At,
    const unsigned short* __restrict__ Winfh,
    const unsigned short* __restrict__ Winfl,
    const unsigned short* __restrict__ Wbcfh,
    const unsigned short* __restrict__ Wbcfl,
    float* __restrict__ hn, float* __restrict__ delta,
    float* __restrict__ Bm, float* __restrict__ Cm,
    float* __restrict__ muv, float* __restrict__ irsv,
    float* __restrict__ EX, float* __restrict__ T) {
  __shared__ float sy[32][36];       // y tile, padded pitch (bank spread)
  __shared__ float sh[32][260];      // hn tile f32, pitch 260
  __shared__ float sB[32][NX];
  __shared__ float sred[32][16];     // per-wave LN/delta partials
  __shared__ float sdelta[32];
  __shared__ float smu[32];
  __shared__ float srstd[32];
  __shared__ __align__(16) unsigned short sChA_h[32 * 256];  // hn bf16 hi (swz)
  __shared__ __align__(16) unsigned short sChA_l[32 * 256];  // hn bf16 lo (swz)
  int t = threadIdx.x;
  int l = t & 63;
  int w = t >> 6;
  int tok0 = blockIdx.x * 32;
  // 1. stage y (32x32 f32)
  if (t < 256) {
    int row = t >> 3, c4 = t & 7;
    *(float4*)&sy[row][c4 * 4] = ((const float4*)(y + (size_t)tok0 * 32))[t];
  }
  __syncthreads();
  // 2. phase A MFMA: build y A-frags (hi/lo), Win B-frags from global
  f32x4 acc[2][2];
  {
    bf16x8 yah[2], yal[2];
    int k0 = (l >> 4) << 3;
    #pragma unroll
    for (int m = 0; m < 2; ++m) {
      int row = m * 16 + (l & 15);
      float4 f0 = *(float4*)&sy[row][k0];
      float4 f1 = *(float4*)&sy[row][k0 + 4];
      float v0 = f0.x, v1 = f0.y, v2 = f0.z, v3 = f0.w;
      float v4 = f1.x, v5 = f1.y, v6 = f1.z, v7 = f1.w;
      unsigned short h0 = f2bf(v0), h1 = f2bf(v1), h2 = f2bf(v2), h3 = f2bf(v3);
      unsigned short h4 = f2bf(v4), h5 = f2bf(v5), h6 = f2bf(v6), h7 = f2bf(v7);
      yah[m][0] = (short)h0; yah[m][1] = (short)h1; yah[m][2] = (short)h2; yah[m][3] = (short)h3;
      yah[m][4] = (short)h4; yah[m][5] = (short)h5; yah[m][6] = (short)h6; yah[m][7] = (short)h7;
      yal[m][0] = (short)f2bf(v0 - bf2f(h0)); yal[m][1] = (short)f2bf(v1 - bf2f(h1));
      yal[m][2] = (short)f2bf(v2 - bf2f(h2)); yal[m][3] = (short)f2bf(v3 - bf2f(h3));
      yal[m][4] = (short)f2bf(v4 - bf2f(h4)); yal[m][5] = (short)f2bf(v5 - bf2f(h5));
      yal[m][6] = (short)f2bf(v6 - bf2f(h6)); yal[m][7] = (short)f2bf(v7 - bf2f(h7));
    }
    const bf16x8* Bh = (const bf16x8*)Winfh;
    const bf16x8* Bl = (const bf16x8*)Winfl;
    #pragma unroll
    for (int n = 0; n < 2; ++n) {
      int tt = w * 2 + n;
      bf16x8 bh = Bh[tt * 64 + l];
      bf16x8 bl = Bl[tt * 64 + l];
      #pragma unroll
      for (int m = 0; m < 2; ++m) {
        f32x4 a = {0.f, 0.f, 0.f, 0.f};
        a = __builtin_amdgcn_mfma_f32_16x16x32_bf16(yah[m], bh, a, 0, 0, 0);
        a = __builtin_amdgcn_mfma_f32_16x16x32_bf16(yal[m], bh, a, 0, 0, 0);
        a = __builtin_amdgcn_mfma_f32_16x16x32_bf16(yah[m], bl, a, 0, 0, 0);
        a = __builtin_amdgcn_mfma_f32_16x16x32_bf16(yal[m], bl, a, 0, 0, 0);
        acc[m][n] = a;
      }
    }
  }
  // bias add: lane's two cols
  int c0 = w * 32 + (l & 15), c1 = c0 + 16;
  {
    float b0 = bin_[c0], b1v = bin_[c1];
    #pragma unroll
    for (int m = 0; m < 2; ++m)
      #pragma unroll
      for (int r = 0; r < 4; ++r) { acc[m][0][r] += b0; acc[m][1][r] += b1v; }
  }
  // 3. LN partial reduce over this wave's 32 cols (16-lane groups)
  {
    #pragma unroll
    for (int m = 0; m < 2; ++m)
      #pragma unroll
      for (int r = 0; r < 4; ++r) {
        float a0 = acc[m][0][r], a1 = acc[m][1][r];
        float s1 = a0 + a1;
        float s2 = a0 * a0 + a1 * a1;
        #pragma unroll
        for (int off = 1; off < 16; off <<= 1) {
          s1 += __shfl_xor(s1, off);
          s2 += __shfl_xor(s2, off);
        }
        if ((l & 15) == 0) {
          int tok = m * 16 + ((l >> 4) << 2) + r;
          sred[tok][w * 2] = s1;
          sred[tok][w * 2 + 1] = s2;
        }
      }
  }
  __syncthreads();
  // 4. combine partials -> mu, rstd (threads 0..31)
  if (t < 32) {
    float s1 = 0.f, s2 = 0.f;
    #pragma unroll
    for (int q = 0; q < 8; ++q) { s1 += sred[t][q * 2]; s2 += sred[t][q * 2 + 1]; }
    float mu = s1 * (1.f / D);
    float var = s2 * (1.f / D) - mu * mu;
    float rstd = rsqrtf(var + 1e-5f);
    smu[t] = mu;
    srstd[t] = rstd;
    muv[tok0 + t] = mu;
    irsv[tok0 + t] = sqrtf(var + 1e-5f);
  }
  __syncthreads();
  // 5. hn = LN(h); write sh f32; delta partial reduce
  {
    float g0 = ng[c0], g1 = ng[c1];
    float nb0 = nb[c0], nb1 = nb[c1];
    float q0 = qd[c0], q1 = qd[c1];
    float ddv[2][4];
    #pragma unroll
    for (int m = 0; m < 2; ++m)
      #pragma unroll
      for (int r = 0; r < 4; ++r) {
        int tok = m * 16 + ((l >> 4) << 2) + r;
        float mu = smu[tok], rstd = srstd[tok];
        float h0 = (acc[m][0][r] - mu) * rstd * g0 + nb0;
        float h1 = (acc[m][1][r] - mu) * rstd * g1 + nb1;
        sh[tok][c0] = h0;
        sh[tok][c1] = h1;
        float dx = h0 * q0 + h1 * q1;
        #pragma unroll
        for (int off = 1; off < 16; off <<= 1) dx += __shfl_xor(dx, off);
        ddv[m][r] = dx;
      }
    if ((l & 15) == 0) {
      #pragma unroll
      for (int m = 0; m < 2; ++m)
        #pragma unroll
        for (int r = 0; r < 4; ++r)
          sred[m * 16 + ((l >> 4) << 2) + r][w] = ddv[m][r];
    }
  }
  __syncthreads();
  // 6. delta combine + T (t<32) ; all threads: sh -> bf16 hi/lo swizzled
  if (t < 32) {
    float dsum = 0.f;
    #pragma unroll
    for (int q = 0; q < 8; ++q) dsum += sred[t][q];
    float xx = pd[0] + dsum;
    float dv = (xx > 20.f) ? xx : log1pf(expf(xx));
    delta[tok0 + t] = dv;
    sdelta[t] = dv;
    float tv = dv;
    #pragma unroll
    for (int off = 1; off < 32; off <<= 1) tv += __shfl_xor(tv, off);
    if (t == 0) T[blockIdx.x] = tv;
  }
  {
    int row = t & 31;
    int cq = (t >> 5) * 16;   // 16 cols per thread
    float4 f0 = *(float4*)&sh[row][cq];
    float4 f1 = *(float4*)&sh[row][cq + 4];
    float4 f2 = *(float4*)&sh[row][cq + 8];
    float4 f3 = *(float4*)&sh[row][cq + 12];
    float vv[16] = {f0.x, f0.y, f0.z, f0.w, f1.x, f1.y, f1.z, f1.w,
                    f2.x, f2.y, f2.z, f2.w, f3.x, f3.y, f3.z, f3.w};
    unsigned hw[8], lw[8];
    #pragma unroll
    for (int p = 0; p < 8; ++p) {
      unsigned short ha = f2bf(vv[2 * p]), hb = f2bf(vv[2 * p + 1]);
      unsigned short la = f2bf(vv[2 * p] - bf2f(ha));
      unsigned short lb = f2bf(vv[2 * p + 1] - bf2f(hb));
      hw[p] = (unsigned)ha | ((unsigned)hb << 16);
      lw[p] = (unsigned)la | ((unsigned)lb << 16);
    }
    unsigned base = (unsigned)row * 512;
    #pragma unroll
    for (int g = 0; g < 2; ++g) {
      unsigned off = ((unsigned)(cq * 2 + g * 16)) ^ ((unsigned)(row & 7) << 4);
      uint4 hv4 = {hw[g * 4], hw[g * 4 + 1], hw[g * 4 + 2], hw[g * 4 + 3]};
      uint4 lv4 = {lw[g * 4], lw[g * 4 + 1], lw[g * 4 + 2], lw[g * 4 + 3]};
      *(uint4*)((char*)sChA_h + base + off) = hv4;
      *(uint4*)((char*)sChA_l + base + off) = lv4;
    }
  }
  __syncthreads();
  // 7. phase C MFMA (waves 0-3); waves 4-7: hn -> global copy (coalesced)
  if (w < 4) {
    int mw = w & 1, nw = w >> 1;
    int row = mw * 16 + (l & 15);
    unsigned abase = (unsigned)row * 512;
    const bf16x8* B2h = (const bf16x8*)Wbcfh;
    const bf16x8* B2l = (const bf16x8*)Wbcfl;
    f32x4 acc2 = {0.f, 0.f, 0.f, 0.f};
    #pragma unroll
    for (int s = 0; s < 8; ++s) {
      unsigned off = ((unsigned)(s * 64 + ((l >> 4) << 4))) ^ ((unsigned)(row & 7) << 4);
      bf16x8 ah = *(const bf16x8*)((const char*)sChA_h + abase + off);
      bf16x8 al = *(const bf16x8*)((const char*)sChA_l + abase + off);
      int bi = (s * 2 + nw) * 64 + l;
      bf16x8 bh = B2h[bi];
      bf16x8 bl = B2l[bi];
      acc2 = __builtin_amdgcn_mfma_f32_16x16x32_bf16(ah, bh, acc2, 0, 0, 0);
      acc2 = __builtin_amdgcn_mfma_f32_16x16x32_bf16(al, bh, acc2, 0, 0, 0);
      acc2 = __builtin_amdgcn_mfma_f32_16x16x32_bf16(ah, bl, acc2, 0, 0, 0);
      acc2 = __builtin_amdgcn_mfma_f32_16x16x32_bf16(al, bl, acc2, 0, 0, 0);
    }
    int tokr = mw * 16 + ((l >> 4) << 2);
    int colc = l & 15;
    if (nw == 0) {
      #pragma unroll
      for (int r = 0; r < 4; ++r) {
        Bm[(size_t)(tok0 + tokr + r) * NX + colc] = acc2[r];
        sB[tokr + r][colc] = acc2[r];
      }
    } else {
      #pragma unroll
      for (int r = 0; r < 4; ++r)
        Cm[(size_t)(tok0 + tokr + r) * NX + colc] = acc2[r];
    }
  } else {
    float4* dst = (float4*)(hn + (size_t)tok0 * D);
    for (int i = t - 256; i < 2048; i += 256) {
      int row = i >> 6, c4 = i & 63;
      dst[i] = *(float4*)&sh[row][c4 * 4];
    }
  }
  __syncthreads();
  // 8. scan: n-split halves; thread = (half, d), x8 in regs.
  {
    int half = t >> 8;          // 0: n=0..7, 1: n=8..15
    int d = t & 255;
    float a8[8], x8[8];
    #pragma unroll
    for (int n = 0; n < 8; ++n) {
      a8[n] = At[(half * 8 + n) * D + d];
      x8[n] = 0.f;
    }
    for (int lo = 0; lo < CL; ++lo) {
      float dlt = sdelta[lo];
      float du = dlt * sh[lo][d];
      #pragma unroll
      for (int n = 0; n < 8; ++n)
        x8[n] = fmaf(exp2f(dlt * a8[n]), x8[n], du * sB[lo][half * 8 + n]);
    }
    size_t exbase = (size_t)blockIdx.x * (NX * D) + d;
    #pragma unroll
    for (int n = 0; n < 8; ++n) EX[exbase + (half * 8 + n) * D] = x8[n];
  }
}

// ---------------- K2b: chunk-level scan, 8-deep prefetch ring --------------
__global__ __launch_bounds__(64) void k2b_chunkscan(
    const float* __restrict__ At, const float* __restrict__ T,
    float* __restrict__ EX) {
  __shared__ float sT[NCH];
  int b = blockIdx.x >> 6;
  int rem = ((blockIdx.x & 63) << 6) | threadIdx.x;  // n*D + d
  sT[threadIdx.x] = T[b * NCH + threadIdx.x];
  __syncthreads();
  float A2 = At[rem];  // already *LOG2E
  size_t base = ((size_t)b << 18) + rem;
  float eq[8];
  #pragma unroll
  for (int j = 0; j < 8; ++j) eq[j] = EX[base + ((size_t)j << 12)];
  float x = 0.f;
  #pragma unroll 8
  for (int c = 0; c < NCH; ++c) {
    float e = eq[c & 7];
    if (c + 8 < NCH) eq[c & 7] = EX[base + ((size_t)(c + 8) << 12)];
    EX[base + ((size_t)c << 12)] = x;
    x = fmaf(exp2f(sT[c] * A2), x, e);
  }
}

__device__ __forceinline__ float gelu_exact(float x) {
  return 0.5f * x * (1.f + erff(x * 0.70710678118654752440f));
}

// ---------------- K2cd: fixup scan + h recon + LN2 + MFMA MLP ---------------
__global__ __launch_bounds__(256) void k2cd_scan_mlp(
    const float* __restrict__ hn, const float* __restrict__ delta,
    const float* __restrict__ Bm, const float* __restrict__ Cm,
    const float* __restrict__ At, const float* __restrict__ EX,
    const float* __restrict__ muv, const float* __restrict__ irsv,
    const float* __restrict__ ng, const float* __restrict__ nb,
    const float* __restrict__ nfg, const float* __restrict__ nfb,
    const unsigned short* __restrict__ W1fh, const unsigned short* __restrict__ W1fl,
    const unsigned short* __restrict__ W2fh, const unsigned short* __restrict__ W2fl,
    const float* __restrict__ b1, const float* __restrict__ b2,
    float* __restrict__ out) {
  __shared__ float s_az[32 * 260];                       // scan output (pre-LN2)
  __shared__ __align__(16) unsigned short sAh[32 * 256]; // bf16 hi (a-tile, then z)
  __shared__ __align__(16) unsigned short sAl[32 * 256]; // bf16 lo
  __shared__ float sB[32][NX];
  __shared__ float sC[32][NX];
  __shared__ float sdelta[32];
  __shared__ float smu[32];
  __shared__ float sirs[32];
  int t = threadIdx.x;
  int tok0 = blockIdx.x * 32;  // blockIdx.x == global chunk index
  size_t tokbase = (size_t)tok0;
  if (t < 32) {
    sdelta[t] = delta[tokbase + t];
    smu[t] = muv[tokbase + t];
    sirs[t] = irsv[tokbase + t];
  }
  for (int i = t; i < 32 * NX; i += 256) {
    ((float*)sB)[i] = Bm[tokbase * NX + i];
    ((float*)sC)[i] = Cm[tokbase * NX + i];
  }
  float a16[16], x16[16];
  size_t exbase = (size_t)blockIdx.x * (NX * D) + t;
  #pragma unroll
  for (int n = 0; n < 16; ++n) {
    a16[n] = At[n * D + t];
    x16[n] = EX[exbase + n * D];
  }
  float nb_d = nb[t];
  float invg = 1.0f / ng[t];
  __syncthreads();
  // scan with true entering state; hn read straight from global (used once)
  for (int lo = 0; lo < CL; ++lo) {
    float hv = hn[(tokbase + lo) * D + t];  // coalesced 1 KB/wave
    float dlt = sdelta[lo];
    float du = dlt * hv;
    float p = 0.f;
    #pragma unroll
    for (int n = 0; n < 16; ++n) {
      x16[n] = fmaf(exp2f(dlt * a16[n]), x16[n], du * sB[lo][n]);
      p = fmaf(x16[n], sC[lo][n], p);
    }
    float h = fmaf((hv - nb_d) * invg, sirs[lo], smu[lo]);
    s_az[lo * 260 + t] = h + p;  // final pre-LN2 value
  }
  __syncthreads();
  // LN2 (wave w owns tokens w*8..+7) -> bf16 hi/lo A-tile, XOR-swizzled
  int dcol = t & 63, jrow = t >> 6;
  int d4 = dcol * 4, j8 = jrow * 8;
  {
    float4 g4 = ((const float4*)nfg)[dcol];
    float4 b4 = ((const float4*)nfb)[dcol];
    for (int jj = 0; jj < 8; ++jj) {
      int lo = j8 + jj;
      float4 v = *(float4*)&s_az[lo * 260 + d4];
      float s1 = v.x + v.y + v.z + v.w;
      float s2 = v.x * v.x + v.y * v.y + v.z * v.z + v.w * v.w;
      #pragma unroll
      for (int off = 1; off < 64; off <<= 1) {
        s1 += __shfl_xor(s1, off);
        s2 += __shfl_xor(s2, off);
      }
      float mu2 = s1 * (1.f / D);
      float var2 = s2 * (1.f / D) - mu2 * mu2;
      float rstd2 = rsqrtf(var2 + 1e-5f);
      float4 o;
      o.x = (v.x - mu2) * rstd2 * g4.x + b4.x;
      o.y = (v.y - mu2) * rstd2 * g4.y + b4.y;
      o.z = (v.z - mu2) * rstd2 * g4.z + b4.z;
      o.w = (v.w - mu2) * rstd2 * g4.w + b4.w;
      unsigned short h0 = f2bf(o.x), h1 = f2bf(o.y), h2 = f2bf(o.z), h3 = f2bf(o.w);
      unsigned short q0 = f2bf(o.x - bf2f(h0));
      unsigned short q1 = f2bf(o.y - bf2f(h1));
      unsigned short q2 = f2bf(o.z - bf2f(h2));
      unsigned short q3 = f2bf(o.w - bf2f(h3));
      unsigned off16 = ((unsigned)(d4 * 2)) ^ ((unsigned)(lo & 7) << 4);
      uint2 hv2, lv2;
      hv2.x = (unsigned)h0 | ((unsigned)h1 << 16);
      hv2.y = (unsigned)h2 | ((unsigned)h3 << 16);
      lv2.x = (unsigned)q0 | ((unsigned)q1 << 16);
      lv2.y = (unsigned)q2 | ((unsigned)q3 << 16);
      *(uint2*)((char*)sAh + lo * 512 + off16) = hv2;
      *(uint2*)((char*)sAl + lo * 512 + off16) = lv2;
    }
  }
  __syncthreads();
  // ---- GEMM1: (32x256) @ W1 (256x256), wave w owns cols [w*64, w*64+64) ----
  int l = t & 63, w = t >> 6;
  const bf16x8* B1h = (const bf16x8*)W1fh;
  const bf16x8* B1l = (const bf16x8*)W1fl;
  f32x4 acc[2][4];
  #pragma unroll
  for (int m = 0; m < 2; ++m)
    #pragma unroll
    for (int n = 0; n < 4; ++n) {
      f32x4 z4 = {0.f, 0.f, 0.f, 0.f};
      acc[m][n] = z4;
    }
  #pragma unroll 2
  for (int s = 0; s < 8; ++s) {
    bf16x8 ah[2], al[2];
    #pragma unroll
    for (int m = 0; m < 2; ++m) {
      int row = m * 16 + (l & 15);
      unsigned off16 = ((unsigned)(s * 64 + ((l >> 4) << 4))) ^ ((unsigned)(row & 7) << 4);
      ah[m] = *(const bf16x8*)((const char*)sAh + row * 512 + off16);
      al[m] = *(const bf16x8*)((const char*)sAl + row * 512 + off16);
    }
    #pragma unroll
    for (int n = 0; n < 4; ++n) {
      int bi = (s * 16 + w * 4 + n) * 64 + l;
      bf16x8 bh = B1h[bi];
      bf16x8 bl = B1l[bi];
      #pragma unroll
      for (int m = 0; m < 2; ++m) {
        acc[m][n] = __builtin_amdgcn_mfma_f32_16x16x32_bf16(ah[m], bh, acc[m][n], 0, 0, 0);
        acc[m][n] = __builtin_amdgcn_mfma_f32_16x16x32_bf16(al[m], bh, acc[m][n], 0, 0, 0);
        acc[m][n] = __builtin_amdgcn_mfma_f32_16x16x32_bf16(ah[m], bl, acc[m][n], 0, 0, 0);
        acc[m][n] = __builtin_amdgcn_mfma_f32_16x16x32_bf16(al[m], bl, acc[m][n], 0, 0, 0);
      }
    }
  }
  __syncthreads();  // all A-tile reads done; sAh/sAl now reused for z
  // ---- b1 + gelu + convert -> z (bf16 hi/lo) back into sAh/sAl ----
  #pragma unroll
  for (int n = 0; n < 4; ++n) {
    int colz = w * 64 + n * 16 + (l & 15);
    float b1v = b1[colz];
    #pragma unroll
    for (int m = 0; m < 2; ++m) {
      #pragma unroll
      for (int r = 0; r < 4; ++r) {
        int row = m * 16 + ((l >> 4) << 2) + r;  // C/D: row=(lane>>4)*4+reg
        float zv = gelu_exact(acc[m][n][r] + b1v);
        unsigned short zh = f2bf(zv);
        unsigned short zl = f2bf(zv - bf2f(zh));
        unsigned off16 = ((unsigned)(colz * 2)) ^ ((unsigned)(row & 7) << 4);
        *(unsigned short*)((char*)sAh + row * 512 + off16) = zh;
        *(unsigned short*)((char*)sAl + row * 512 + off16) = zl;
      }
    }
  }
  __syncthreads();
  // ---- GEMM2: z (32x256) @ W2 (256x32); wave w -> (mw=w>>1, nw=w&1) ----
  int mw = w >> 1, nw = w & 1;
  const bf16x8* B2h = (const bf16x8*)W2fh;
  const bf16x8* B2l = (const bf16x8*)W2fl;
  f32x4 acc2 = {0.f, 0.f, 0.f, 0.f};
  #pragma unroll 2
  for (int s = 0; s < 8; ++s) {
    int row = mw * 16 + (l & 15);
    unsigned off16 = ((unsigned)(s * 64 + ((l >> 4) << 4))) ^ ((unsigned)(row & 7) << 4);
    bf16x8 zh8 = *(const bf16x8*)((const char*)sAh + row * 512 + off16);
    bf16x8 zl8 = *(const bf16x8*)((const char*)sAl + row * 512 + off16);
    int bi = (s * 2 + nw) * 64 + l;
    bf16x8 bh = B2h[bi];
    bf16x8 bl = B2l[bi];
    acc2 = __builtin_amdgcn_mfma_f32_16x16x32_bf16(zh8, bh, acc2, 0, 0, 0);
    acc2 = __builtin_amdgcn_mfma_f32_16x16x32_bf16(zl8, bh, acc2, 0, 0, 0);
    acc2 = __builtin_amdgcn_mfma_f32_16x16x32_bf16(zh8, bl, acc2, 0, 0, 0);
    acc2 = __builtin_amdgcn_mfma_f32_16x16x32_bf16(zl8, bl, acc2, 0, 0, 0);
  }
  int colo = nw * 16 + (l & 15);
  float b2v = b2[colo];
  #pragma unroll
  for (int r = 0; r < 4; ++r) {
    int row = mw * 16 + ((l >> 4) << 2) + r;
    out[(size_t)(tok0 + row) * 32 + colo] = acc2[r] + b2v;
  }
}

extern "C" void kernel_launch(void* const* d_in, const int* in_sizes, int n_in,
                              void* d_out, int out_size, void* d_ws, size_t ws_size,
                              hipStream_t stream) {
  const float* y    = (const float*)d_in[0];
  const float* Win  = (const float*)d_in[1];
  const float* bin_ = (const float*)d_in[2];
  const float* ng   = (const float*)d_in[3];
  const float* nb   = (const float*)d_in[4];
  const float* A    = (const float*)d_in[5];
  const float* WB   = (const float*)d_in[6];
  const float* WC   = (const float*)d_in[7];
  const float* qd   = (const float*)d_in[8];
  const float* pd   = (const float*)d_in[9];
  const float* nfg  = (const float*)d_in[10];
  const float* nfb  = (const float*)d_in[11];
  const float* W1   = (const float*)d_in[12];
  const float* b1   = (const float*)d_in[13];
  const float* W2   = (const float*)d_in[14];
  const float* b2   = (const float*)d_in[15];

  float* ws = (float*)d_ws;
  float* hnbuf = ws;                          // NTOK*D
  float* delta = ws + 4194304;                // NTOK
  float* Bm    = delta + NTOK;                // NTOK*NX
  float* Cm    = Bm + NTOK * NX;              // NTOK*NX
  float* muv   = Cm + NTOK * NX;              // NTOK
  float* irsv  = muv + NTOK;                  // NTOK
  float* Tbuf  = irsv + NTOK;                 // 512
  float* At    = Tbuf + NBATCH * NCH;         // 4096
  float* EX    = At + D * NX;                 // 512*4096 = 2M floats
  // bf16 fragment-packed weights (hi/lo)
  unsigned short* W1fh  = (unsigned short*)(EX + 2097152);  // 65536
  unsigned short* W1fl  = W1fh + 65536;                     // 65536
  unsigned short* W2fh  = W1fl + 65536;                     // 8192
  unsigned short* W2fl  = W2fh + 8192;                      // 8192
  unsigned short* Winfh = W2fl + 8192;                      // 8192
  unsigned short* Winfl = Winfh + 8192;                     // 8192
  unsigned short* Wbcfh = Winfl + 8192;                     // 8192
  unsigned short* Wbcfl = Wbcfh + 8192;                     // 8192

  k0_prep<<<368, 256, 0, stream>>>(A, WB, WC, Win, W1, W2, At,
                                   W1fh, W1fl, W2fh, W2fl,
                                   Winfh, Winfl, Wbcfh, Wbcfl);
  k1a_front_scan<<<NTOK / 32, 512, 0, stream>>>(y, bin_, ng, nb, qd, pd, At,
                                                Winfh, Winfl, Wbcfh, Wbcfl,
                                                hnbuf, delta, Bm, Cm,
                                                muv, irsv, EX, Tbuf);
  k2b_chunkscan<<<NBATCH * 64, 64, 0, stream>>>(At, Tbuf, EX);
  k2cd_scan_mlp<<<NTOK / 32, 256, 0, stream>>>(hnbuf, delta, Bm, Cm, At, EX,
                                               muv, irsv, ng, nb, nfg, nfb,
                                               W1fh, W1fl, W2fh, W2fl,
                                               b1, b2, (float*)d_out);
}